// Round 8
// baseline (2174.634 us; speedup 1.0000x reference)
//
#include <hip/hip_runtime.h>

typedef unsigned short US;
typedef unsigned int   UI;
typedef short  short8 __attribute__((ext_vector_type(8)));
typedef US     u16x8  __attribute__((ext_vector_type(8)));
typedef float  f32x4  __attribute__((ext_vector_type(4)));

#define DEVI __device__ __forceinline__

DEVI float bf2f(US u){ UI i = ((UI)u) << 16; float f; __builtin_memcpy(&f, &i, 4); return f; }
DEVI US f2bf(float x){ UI i; __builtin_memcpy(&i, &x, 4); UI r = (i + 0x7FFFu + ((i >> 16) & 1u)) >> 16; return (US)r; }
// erf via Abramowitz-Stegun 7.1.26 (|eps| <= 1.5e-7; exact at bf16 precision)
DEVI float erf_fast(float z){
    float az = fabsf(z);
    float t = 1.0f / fmaf(0.3275911f, az, 1.0f);
    float p = t * fmaf(t, fmaf(t, fmaf(t, fmaf(t, 1.061405429f, -1.453152027f),
                 1.421413741f), -0.284496736f), 0.254829592f);
    float e = __expf(-az * az);
    float er = fmaf(-p, e, 1.0f);
    return copysignf(er, z);
}
DEVI float gelu_f(float x){ return 0.5f * x * (1.0f + erf_fast(x * 0.70710678118654752f)); }
DEVI UI encf(float f){ UI u; __builtin_memcpy(&u, &f, 4); return (u & 0x80000000u) ? ~u : (u | 0x80000000u); }
DEVI float decf(UI u){ UI b = (u & 0x80000000u) ? (u ^ 0x80000000u) : ~u; float f; __builtin_memcpy(&f, &b, 4); return f; }
DEVI int swz(int r, int c, int ld){ int i = r * ld + c; return i ^ ((r & 7) << 3); }

// bf16 weight-buffer offsets (elements)
enum : int { O_EmW1 = 0, O_EmWh = 131072, O_EmWo = 147456, O_RhoW1 = 212992,
             O_RhoWh = 344064, O_RhoWo = 360448, O_Cat1 = 368640, O_Cat2 = 376832,
             O_Cat3 = 385024, O_H1W1 = 393216, O_H1Wh = 442368, O_H1Wo = 458752,
             O_H2W1 = 475136, O_H2Wh = 491520, W_TOTAL = 507904 };

// ---------------------------------------------------------------------------
// Generic W-streaming stage (embed/rho): NTHR threads, wave tile
// 16 rows x NT*16 cols (wc = (w&1)).
// ---------------------------------------------------------------------------
template<int NT, int NKC, int NTHR>
DEVI void stageW(const US* __restrict__ Wg, int Kw, const US* __restrict__ A, int lda,
                 int ab0, int ab1, int ab2, int arow0, US* Wb, int tid, f32x4 (&acc)[NT])
{
    const int lane = tid & 63;
    const int wc = (tid >> 6) & 1;
    #pragma unroll
    for (int n = 0; n < NT; ++n) acc[n] = (f32x4){0.f, 0.f, 0.f, 0.f};
    constexpr int J = (NT * 256) / NTHR;
    u16x8 wreg[J];
    #pragma unroll
    for (int j = 0; j < J; ++j) {
        const int c = tid + NTHR * j;
        wreg[j] = *(const u16x8*)(Wg + (size_t)(c >> 3) * Kw + (c & 7) * 8);
    }
    #pragma unroll
    for (int kc = 0; kc < NKC; ++kc) {
        __syncthreads();
        #pragma unroll
        for (int j = 0; j < J; ++j) {
            const int c = tid + NTHR * j;
            *(u16x8*)&Wb[swz(c >> 3, (c & 7) * 8, 64)] = wreg[j];
        }
        __syncthreads();
        if (kc + 1 < NKC) {
            #pragma unroll
            for (int j = 0; j < J; ++j) {
                const int c = tid + NTHR * j;
                wreg[j] = *(const u16x8*)(Wg + (size_t)(c >> 3) * Kw + (kc + 1) * 64 + (c & 7) * 8);
            }
        }
        const int ab = (kc == 0) ? ab0 : ((kc == 1) ? ab1 : ab2);
        #pragma unroll
        for (int sub = 0; sub < 2; ++sub) {
            const int kk = sub * 32 + ((lane >> 4) << 3);
            short8 a = *(const short8*)&A[swz(arow0 + (lane & 15), ab + kk, lda)];
            #pragma unroll
            for (int n = 0; n < NT; ++n) {
                short8 b = *(const short8*)&Wb[swz(wc * (NT * 16) + n * 16 + (lane & 15), kk, 64)];
                acc[n] = __builtin_amdgcn_mfma_f32_16x16x32_bf16(a, b, acc[n], 0, 0, 0);
            }
        }
    }
    __syncthreads();
}

// ---------------------------------------------------------------------------
// 1024-thread (16-wave) stage: wave w owns rows w*16..+15 of A (lda=256),
// all 128 out cols. W slab [128 x 64] (16 KB) single-buffered.
// ---------------------------------------------------------------------------
template<int NKC>
DEVI void stage16W(const US* __restrict__ Wg, int Kw, const US* __restrict__ A,
                   int ab0, int ab1, US* Wb, int tid, f32x4 (&acc)[8])
{
    const int lane = tid & 63;
    const int w = tid >> 6;
    #pragma unroll
    for (int n = 0; n < 8; ++n) acc[n] = (f32x4){0.f, 0.f, 0.f, 0.f};
    u16x8 wreg = *(const u16x8*)(Wg + (size_t)(tid >> 3) * Kw + (tid & 7) * 8);
    #pragma unroll
    for (int kc = 0; kc < NKC; ++kc) {
        __syncthreads();
        *(u16x8*)&Wb[swz(tid >> 3, (tid & 7) * 8, 64)] = wreg;
        __syncthreads();
        if (kc + 1 < NKC)
            wreg = *(const u16x8*)(Wg + (size_t)(tid >> 3) * Kw + (kc + 1) * 64 + (tid & 7) * 8);
        const int ab = (kc == 0) ? ab0 : ab1;
        #pragma unroll
        for (int sub = 0; sub < 2; ++sub) {
            const int kk = sub * 32 + ((lane >> 4) << 3);
            short8 a = *(const short8*)&A[swz(w * 16 + (lane & 15), ab + kk, 256)];
            #pragma unroll
            for (int n = 0; n < 8; ++n) {
                short8 b = *(const short8*)&Wb[swz(n * 16 + (lane & 15), kk, 64)];
                acc[n] = __builtin_amdgcn_mfma_f32_16x16x32_bf16(a, b, acc[n], 0, 0, 0);
            }
        }
    }
    __syncthreads();
}

// Same, but A-fragments from registers (zf[3][2], static indexing).
template<int NKC>
DEVI void stage16R(const US* __restrict__ Wg, int Kw, const u16x8 (&zf)[3][2],
                   US* Wb, int tid, f32x4 (&acc)[8])
{
    const int lane = tid & 63;
    #pragma unroll
    for (int n = 0; n < 8; ++n) acc[n] = (f32x4){0.f, 0.f, 0.f, 0.f};
    u16x8 wreg = *(const u16x8*)(Wg + (size_t)(tid >> 3) * Kw + (tid & 7) * 8);
    #pragma unroll
    for (int kc = 0; kc < NKC; ++kc) {
        __syncthreads();
        *(u16x8*)&Wb[swz(tid >> 3, (tid & 7) * 8, 64)] = wreg;
        __syncthreads();
        if (kc + 1 < NKC)
            wreg = *(const u16x8*)(Wg + (size_t)(tid >> 3) * Kw + (kc + 1) * 64 + (tid & 7) * 8);
        #pragma unroll
        for (int sub = 0; sub < 2; ++sub) {
            const int kk = sub * 32 + ((lane >> 4) << 3);
            short8 a;
            __builtin_memcpy(&a, &zf[kc][sub], 16);
            #pragma unroll
            for (int n = 0; n < 8; ++n) {
                short8 b = *(const short8*)&Wb[swz(n * 16 + (lane & 15), kk, 64)];
                acc[n] = __builtin_amdgcn_mfma_f32_16x16x32_bf16(a, b, acc[n], 0, 0, 0);
            }
        }
    }
    __syncthreads();
}

// ---------------------------------------------------------------------------
// Fused embedder: 128 point-rows (16 nodes) per block, 1024 threads (16 waves).
// S3 merged: 2 passes of NT=8 (256 cols each) instead of 4 passes of NT=4.
// ---------------------------------------------------------------------------
__global__ __launch_bounds__(1024, 4)
void embed_fused(const float* __restrict__ x, const US* __restrict__ WB,
                 const float* __restrict__ b_in, const float* __restrict__ b_proj,
                 const float* __restrict__ b_hid, const float* __restrict__ b_out,
                 US* __restrict__ Ss)
{
    __shared__ __align__(16) US T1[128 * 256];
    __shared__ __align__(16) US Wb[256 * 64];
    __shared__ __align__(16) US As[128 * 64];
    const int tid = threadIdx.x, lane = tid & 63, w = tid >> 6;
    const int wr = w >> 1, wc = w & 1;
    const int grow0 = blockIdx.x * 128;
    const int row0 = wr * 16 + ((lane >> 4) << 2);

    { // ---- stage 1: out 256, K=512 (8 kc) ----
        f32x4 acc[8];
        #pragma unroll
        for (int n = 0; n < 8; ++n) acc[n] = (f32x4){0.f, 0.f, 0.f, 0.f};
        const float* xr = x + (size_t)(grow0 + (tid >> 3)) * 512 + (tid & 7) * 8;
        float4 a0, a1;
        u16x8 wreg[2];
        auto loadA = [&](int kc) { a0 = *(const float4*)(xr + kc * 64); a1 = *(const float4*)(xr + kc * 64 + 4); };
        auto loadW = [&](int kc) {
            #pragma unroll
            for (int j = 0; j < 2; ++j) {
                const int c = tid + 1024 * j;
                wreg[j] = *(const u16x8*)(WB + O_EmW1 + (size_t)(c >> 3) * 512 + kc * 64 + (c & 7) * 8);
            }
        };
        loadA(0); loadW(0);
        for (int kc = 0; kc < 8; ++kc) {
            __syncthreads();
            {
                u16x8 v;
                v[0] = f2bf(a0.x); v[1] = f2bf(a0.y); v[2] = f2bf(a0.z); v[3] = f2bf(a0.w);
                v[4] = f2bf(a1.x); v[5] = f2bf(a1.y); v[6] = f2bf(a1.z); v[7] = f2bf(a1.w);
                *(u16x8*)&As[swz(tid >> 3, (tid & 7) * 8, 64)] = v;
                #pragma unroll
                for (int j = 0; j < 2; ++j) {
                    const int c = tid + 1024 * j;
                    *(u16x8*)&Wb[swz(c >> 3, (c & 7) * 8, 64)] = wreg[j];
                }
            }
            __syncthreads();
            if (kc < 7) { loadA(kc + 1); loadW(kc + 1); }
            #pragma unroll
            for (int sub = 0; sub < 2; ++sub) {
                const int kk = sub * 32 + ((lane >> 4) << 3);
                short8 a = *(const short8*)&As[swz(wr * 16 + (lane & 15), kk, 64)];
                #pragma unroll
                for (int n = 0; n < 8; ++n) {
                    short8 b = *(const short8*)&Wb[swz(wc * 128 + n * 16 + (lane & 15), kk, 64)];
                    acc[n] = __builtin_amdgcn_mfma_f32_16x16x32_bf16(a, b, acc[n], 0, 0, 0);
                }
            }
        }
        __syncthreads();
        #pragma unroll
        for (int n = 0; n < 8; ++n) {
            const int col = wc * 128 + n * 16 + (lane & 15);
            const float bv = (col < 128) ? b_in[col] : b_proj[col - 128];
            #pragma unroll
            for (int r = 0; r < 4; ++r) {
                float v = acc[n][r] + bv;
                if (col < 128) v = gelu_f(v);
                T1[swz(row0 + r, col, 256)] = f2bf(v);
            }
        }
    }
    { // ---- stage 2: U = s + gelu(t1@Wh+bh) -> T1 lo ----
        f32x4 acc[4];
        stageW<4, 2, 1024>(WB + O_EmWh, 128, T1, 256, 0, 64, 0, wr * 16, Wb, tid, acc);
        #pragma unroll
        for (int n = 0; n < 4; ++n) {
            const int col = wc * 64 + n * 16 + (lane & 15);
            const float bv = b_hid[col];
            #pragma unroll
            for (int r = 0; r < 4; ++r) {
                const float sv = bf2f(T1[swz(row0 + r, 128 + col, 256)]);
                T1[swz(row0 + r, col, 256)] = f2bf(gelu_f(acc[n][r] + bv) + sv);
            }
        }
    }
    // ---- stage 3: 2 merged passes (NT=8, 256 cols each), sum8 epilogue ----
    for (int p2 = 0; p2 < 2; ++p2) {
        f32x4 acc[8];
        stageW<8, 2, 1024>(WB + O_EmWo + (size_t)(p2 * 256) * 128, 128, T1, 256, 0, 64, 0, wr * 16, Wb, tid, acc);
        #pragma unroll
        for (int n = 0; n < 8; ++n) {
            const int col = wc * 128 + n * 16 + (lane & 15);
            const float bv = b_out[p2 * 256 + col];
            float s = 0.f;
            #pragma unroll
            for (int r = 0; r < 4; ++r) s += gelu_f(acc[n][r] + bv);
            s += __shfl_xor(s, 16);
            if (((lane >> 4) & 1) == 0) {
                const int node = (grow0 >> 3) + wr * 2 + (lane >> 5);
                Ss[(size_t)node * 512 + p2 * 256 + col] = f2bf(s);
            }
        }
    }
}

// ---------------------------------------------------------------------------
// Fused rho: 64 nodes per block, 512 threads (unchanged from R7).
// ---------------------------------------------------------------------------
__global__ __launch_bounds__(512, 2)
void rho_fused(const US* __restrict__ Ss, const US* __restrict__ WB,
               const float* __restrict__ b_in, const float* __restrict__ b_proj,
               const float* __restrict__ b_hid, const float* __restrict__ b_out,
               US* __restrict__ zo, int N)
{
    __shared__ __align__(16) US T1[64 * 256];
    __shared__ __align__(16) US Wb[256 * 64];
    __shared__ __align__(16) US As[64 * 64];
    const int tid = threadIdx.x, lane = tid & 63, w = tid >> 6;
    const int wr = w >> 1, wc = w & 1;
    const int grow0 = blockIdx.x * 64;
    const int row0 = wr * 16 + ((lane >> 4) << 2);

    { // ---- stage 1: out 256, K=512 ----
        f32x4 acc[8];
        #pragma unroll
        for (int n = 0; n < 8; ++n) acc[n] = (f32x4){0.f, 0.f, 0.f, 0.f};
        int arow = grow0 + (tid >> 3); if (arow >= N) arow = N - 1;
        const US* srow = Ss + (size_t)arow * 512 + (tid & 7) * 8;
        u16x8 areg, wreg[4];
        auto loadA = [&](int kc) { areg = *(const u16x8*)(srow + kc * 64); };
        auto loadW = [&](int kc) {
            #pragma unroll
            for (int j = 0; j < 4; ++j) {
                const int c = tid + 512 * j;
                wreg[j] = *(const u16x8*)(WB + O_RhoW1 + (size_t)(c >> 3) * 512 + kc * 64 + (c & 7) * 8);
            }
        };
        loadA(0); loadW(0);
        for (int kc = 0; kc < 8; ++kc) {
            __syncthreads();
            *(u16x8*)&As[swz(tid >> 3, (tid & 7) * 8, 64)] = areg;
            #pragma unroll
            for (int j = 0; j < 4; ++j) {
                const int c = tid + 512 * j;
                *(u16x8*)&Wb[swz(c >> 3, (c & 7) * 8, 64)] = wreg[j];
            }
            __syncthreads();
            if (kc < 7) { loadA(kc + 1); loadW(kc + 1); }
            #pragma unroll
            for (int sub = 0; sub < 2; ++sub) {
                const int kk = sub * 32 + ((lane >> 4) << 3);
                short8 a = *(const short8*)&As[swz(wr * 16 + (lane & 15), kk, 64)];
                #pragma unroll
                for (int n = 0; n < 8; ++n) {
                    short8 b = *(const short8*)&Wb[swz(wc * 128 + n * 16 + (lane & 15), kk, 64)];
                    acc[n] = __builtin_amdgcn_mfma_f32_16x16x32_bf16(a, b, acc[n], 0, 0, 0);
                }
            }
        }
        __syncthreads();
        #pragma unroll
        for (int n = 0; n < 8; ++n) {
            const int col = wc * 128 + n * 16 + (lane & 15);
            const float bv = (col < 128) ? b_in[col] : b_proj[col - 128];
            #pragma unroll
            for (int r = 0; r < 4; ++r) {
                float v = acc[n][r] + bv;
                if (col < 128) v = gelu_f(v);
                T1[swz(row0 + r, col, 256)] = f2bf(v);
            }
        }
    }
    { // ---- stage 2: RU -> T1 lo ----
        f32x4 acc[4];
        stageW<4, 2, 512>(WB + O_RhoWh, 128, T1, 256, 0, 64, 0, wr * 16, Wb, tid, acc);
        #pragma unroll
        for (int n = 0; n < 4; ++n) {
            const int col = wc * 64 + n * 16 + (lane & 15);
            const float bv = b_hid[col];
            #pragma unroll
            for (int r = 0; r < 4; ++r) {
                const float sv = bf2f(T1[swz(row0 + r, 128 + col, 256)]);
                T1[swz(row0 + r, col, 256)] = f2bf(gelu_f(acc[n][r] + bv) + sv);
            }
        }
    }
    { // ---- stage 3: out 64 ----
        f32x4 acc[2];
        stageW<2, 2, 512>(WB + O_RhoWo, 128, T1, 256, 0, 64, 0, wr * 16, Wb, tid, acc);
        #pragma unroll
        for (int n = 0; n < 2; ++n) {
            const int col = wc * 32 + n * 16 + (lane & 15);
            const float bv = b_out[col];
            #pragma unroll
            for (int r = 0; r < 4; ++r) {
                const int node = grow0 + row0 + r;
                if (node < N) zo[(size_t)node * 64 + col] = f2bf(acc[n][r] + bv);
            }
        }
    }
}

// ---------------------------------------------------------------------------
// Fused head v4: 128 queries/block, 1024 threads (16 waves), both sides.
// T1 rows 0-127 = xy, 128-255 = yx. Wave w owns rows w*16..+15 (side = w>>3).
// 16 waves come from ONE block -> residency guaranteed; flat-workgroup-size
// 1024 caps regs at 128/wave (no R7-style 2-block dependency).
// LDS: T1 128KB + Wb 16KB = 144.5KB -> 1 block/CU, 16 waves.
// ---------------------------------------------------------------------------
__global__ __launch_bounds__(1024, 4)
void head_fused(const int* __restrict__ srcq, const int* __restrict__ dstq,
                const int* __restrict__ batch, const US* __restrict__ z,
                const US* __restrict__ geb, const US* __restrict__ WB,
                const float* __restrict__ b1_in, const float* __restrict__ b1_proj,
                const float* __restrict__ b1_hid, const float* __restrict__ b1_out,
                const float* __restrict__ b2_in, const float* __restrict__ b2_hid,
                const float* __restrict__ w2_out, const float* __restrict__ b2_out,
                float* __restrict__ outH, float* __restrict__ outXY, int Q)
{
    __shared__ __align__(16) US T1[256 * 256];
    __shared__ __align__(16) US Wb[128 * 64];
    const int tid = threadIdx.x, lane = tid & 63, w = tid >> 6;
    const int q0 = blockIdx.x * 128;
    const int row0 = w * 16 + ((lane >> 4) << 2);   // C-frag row base in T1

    // ---- xy output pass (global->global, coalesced; independent) ----
    {
        const int r = tid >> 3, h = tid & 7;        // 128 queries x 8 threads
        const int qq = q0 + r;
        if (qq < Q) {
            const int sr = srcq[qq], dr = dstq[qq];
            const int gr = batch[sr];
            u16x8 a = *(const u16x8*)(z + (size_t)sr * 64 + h * 8);
            u16x8 b = *(const u16x8*)(z + (size_t)dr * 64 + h * 8);
            u16x8 c = *(const u16x8*)(geb + (size_t)gr * 64 + h * 8);
            float* xr = outXY + (size_t)qq * 192;
            float4 f;
            f.x = bf2f(a[0]); f.y = bf2f(a[1]); f.z = bf2f(a[2]); f.w = bf2f(a[3]); *(float4*)&xr[h * 8] = f;
            f.x = bf2f(a[4]); f.y = bf2f(a[5]); f.z = bf2f(a[6]); f.w = bf2f(a[7]); *(float4*)&xr[h * 8 + 4] = f;
            f.x = bf2f(b[0]); f.y = bf2f(b[1]); f.z = bf2f(b[2]); f.w = bf2f(b[3]); *(float4*)&xr[64 + h * 8] = f;
            f.x = bf2f(b[4]); f.y = bf2f(b[5]); f.z = bf2f(b[6]); f.w = bf2f(b[7]); *(float4*)&xr[64 + h * 8 + 4] = f;
            f.x = bf2f(c[0]); f.y = bf2f(c[1]); f.z = bf2f(c[2]); f.w = bf2f(c[3]); *(float4*)&xr[128 + h * 8] = f;
            f.x = bf2f(c[4]); f.y = bf2f(c[5]); f.z = bf2f(c[6]); f.w = bf2f(c[7]); *(float4*)&xr[128 + h * 8 + 4] = f;
        }
    }

    // ---- load S1 A-fragments to registers ----
    u16x8 zf[3][2];
    {
        const int side = w >> 3;
        int q = q0 + ((w & 7) * 16 + (lane & 15));   // this lane's query row
        if (q >= Q) q = Q - 1;
        const int s_ = srcq[q], d_ = dstq[q];
        const int g_ = batch[s_];
        const US* p0 = side ? (z + (size_t)d_ * 64) : (z + (size_t)s_ * 64);
        const US* p1 = side ? (z + (size_t)s_ * 64) : (z + (size_t)d_ * 64);
        const US* p2 = geb + (size_t)g_ * 64;
        const int ko = (lane >> 4) << 3;
        zf[0][0] = *(const u16x8*)(p0 + ko);      zf[0][1] = *(const u16x8*)(p0 + 32 + ko);
        zf[1][0] = *(const u16x8*)(p1 + ko);      zf[1][1] = *(const u16x8*)(p1 + 32 + ko);
        zf[2][0] = *(const u16x8*)(p2 + ko);      zf[2][1] = *(const u16x8*)(p2 + 32 + ko);
    }

    f32x4 acc[8];
    // S1p0: t1 = gelu(A@W1in + b) -> T1 lo
    stage16R<3>(WB + O_H1W1, 192, zf, Wb, tid, acc);
    #pragma unroll
    for (int n = 0; n < 8; ++n) {
        const int col = n * 16 + (lane & 15);
        const float bv = b1_in[col];
        #pragma unroll
        for (int r = 0; r < 4; ++r)
            T1[swz(row0 + r, col, 256)] = f2bf(gelu_f(acc[n][r] + bv));
    }
    // S1p1: s1 = A@Wproj + b -> T1 hi
    stage16R<3>(WB + O_H1W1 + 128 * 192, 192, zf, Wb, tid, acc);
    #pragma unroll
    for (int n = 0; n < 8; ++n) {
        const int col = n * 16 + (lane & 15);
        const float bv = b1_proj[col];
        #pragma unroll
        for (int r = 0; r < 4; ++r)
            T1[swz(row0 + r, 128 + col, 256)] = f2bf(acc[n][r] + bv);
    }
    // S2: U = s1 + gelu(t1@Wh + bh) -> T1 lo
    stage16W<2>(WB + O_H1Wh, 128, T1, 0, 64, Wb, tid, acc);
    #pragma unroll
    for (int n = 0; n < 8; ++n) {
        const int col = n * 16 + (lane & 15);
        const float bv = b1_hid[col];
        #pragma unroll
        for (int r = 0; r < 4; ++r) {
            const float sv = bf2f(T1[swz(row0 + r, 128 + col, 256)]);
            T1[swz(row0 + r, col, 256)] = f2bf(gelu_f(acc[n][r] + bv) + sv);
        }
    }
    // S3: T = relu(U@Wo + bo) -> T1 hi
    stage16W<2>(WB + O_H1Wo, 128, T1, 0, 64, Wb, tid, acc);
    #pragma unroll
    for (int n = 0; n < 8; ++n) {
        const int col = n * 16 + (lane & 15);
        const float bv = b1_out[col];
        #pragma unroll
        for (int r = 0; r < 4; ++r)
            T1[swz(row0 + r, 128 + col, 256)] = f2bf(fmaxf(acc[n][r] + bv, 0.f));
    }
    // S4: B1 = gelu(T@W2 + b2) -> T1 lo (A = T1 hi)
    stage16W<2>(WB + O_H2W1, 128, T1, 128, 192, Wb, tid, acc);
    #pragma unroll
    for (int n = 0; n < 8; ++n) {
        const int col = n * 16 + (lane & 15);
        const float bv = b2_in[col];
        #pragma unroll
        for (int r = 0; r < 4; ++r)
            T1[swz(row0 + r, col, 256)] = f2bf(gelu_f(acc[n][r] + bv));
    }
    // S5: U2 = T + gelu(B1@Wh2 + bh2) -> T1 lo
    stage16W<2>(WB + O_H2Wh, 128, T1, 0, 64, Wb, tid, acc);
    #pragma unroll
    for (int n = 0; n < 8; ++n) {
        const int col = n * 16 + (lane & 15);
        const float bv = b2_hid[col];
        #pragma unroll
        for (int r = 0; r < 4; ++r) {
            const float tv = bf2f(T1[swz(row0 + r, 128 + col, 256)]);
            T1[swz(row0 + r, col, 256)] = f2bf(gelu_f(acc[n][r] + bv) + tv);
        }
    }
    // wout into Wb space (all Wb reads done: stage16W ends with a barrier)
    float* wout_f = (float*)Wb;
    if (tid < 128) wout_f[tid] = w2_out[tid];
    __syncthreads();
    // S6: scalar head: 256 rows x 4 threads, 32 cols each
    {
        const int r = tid >> 2, h = tid & 3;
        float a = 0.f;
        #pragma unroll
        for (int j = 0; j < 4; ++j) {
            u16x8 v = *(const u16x8*)&T1[swz(r, h * 32 + 8 * j, 256)];
            #pragma unroll
            for (int e = 0; e < 8; ++e) a += bf2f(v[e]) * wout_f[h * 32 + 8 * j + e];
        }
        a += __shfl_xor(a, 1);
        a += __shfl_xor(a, 2);
        const int qq = q0 + (r & 127);
        if (h == 0 && qq < Q) outH[(size_t)(r >> 7) * Q + qq] = a + b2_out[0];
    }
}

// ---------------------------------------------------------------------------
// SAGE layer: zout = zin + gelu( [agg|zin] @ Wcat^T + bl ), K=128, out 64
// ---------------------------------------------------------------------------
__global__ __launch_bounds__(256, 2)
void sage_gemm(const US* __restrict__ zin, const US* __restrict__ agg,
               const US* __restrict__ Wc, const float* __restrict__ bias,
               US* __restrict__ zout, int N)
{
    __shared__ __align__(16) US As[128 * 128];
    __shared__ __align__(16) US Ws[64 * 128];
    const int tid = threadIdx.x, lane = tid & 63, w = tid >> 6;
    const int grow0 = blockIdx.x * 128;
    {
        const int r = tid >> 1, h = tid & 1;
        int row = grow0 + r; if (row >= N) row = N - 1;
        const US* src = h ? (zin + (size_t)row * 64) : (agg + (size_t)row * 64);
        #pragma unroll
        for (int j = 0; j < 8; ++j)
            *(u16x8*)&As[swz(r, h * 64 + 8 * j, 128)] = *(const u16x8*)(src + 8 * j);
    }
    #pragma unroll
    for (int j = 0; j < 4; ++j) {
        const int c = tid + 256 * j;
        *(u16x8*)&Ws[swz(c >> 4, (c & 15) * 8, 128)] =
            *(const u16x8*)(Wc + (size_t)(c >> 4) * 128 + (c & 15) * 8);
    }
    __syncthreads();
    const int rbw = w * 32;
    f32x4 acc[2][4];
    #pragma unroll
    for (int m = 0; m < 2; ++m)
        #pragma unroll
        for (int n = 0; n < 4; ++n) acc[m][n] = (f32x4){0.f, 0.f, 0.f, 0.f};
    #pragma unroll
    for (int kc = 0; kc < 2; ++kc)
        #pragma unroll
        for (int sub = 0; sub < 2; ++sub) {
            const int kk = kc * 64 + sub * 32 + ((lane >> 4) << 3);
            short8 a[2], b[4];
            #pragma unroll
            for (int m = 0; m < 2; ++m) a[m] = *(const short8*)&As[swz(rbw + m * 16 + (lane & 15), kk, 128)];
            #pragma unroll
            for (int n = 0; n < 4; ++n) b[n] = *(const short8*)&Ws[swz(n * 16 + (lane & 15), kk, 128)];
            #pragma unroll
            for (int m = 0; m < 2; ++m)
                #pragma unroll
                for (int n = 0; n < 4; ++n)
                    acc[m][n] = __builtin_amdgcn_mfma_f32_16x16x32_bf16(a[m], b[n], acc[m][n], 0, 0, 0);
        }
    #pragma unroll
    for (int m = 0; m < 2; ++m) {
        const int row0 = rbw + m * 16 + ((lane >> 4) << 2);
        #pragma unroll
        for (int n = 0; n < 4; ++n) {
            const int col = n * 16 + (lane & 15);
            const float bv = bias[col];
            #pragma unroll
            for (int r = 0; r < 4; ++r) {
                const int node = grow0 + row0 + r;
                if (node < N) {
                    const float v = gelu_f(acc[m][n][r] + bv) + bf2f(zin[(size_t)node * 64 + col]);
                    zout[(size_t)node * 64 + col] = f2bf(v);
                }
            }
        }
    }
}

// ---------------------------------------------------------------------------
// Weight prep (f32 -> bf16, strided stacking)
// ---------------------------------------------------------------------------
struct WSeg { const float* src; int dst; int n; int rl; int ldd; };
struct WPrm { WSeg s[20]; };

__global__ void prep_w(WPrm p, US* __restrict__ wb)
{
    WSeg sg = p.s[blockIdx.x];
    for (int i = threadIdx.x; i < sg.n; i += 256) {
        const int idx = sg.dst + (i / sg.rl) * sg.ldd + (i % sg.rl);
        wb[idx] = f2bf(sg.src[i]);
    }
}

// ---------------------------------------------------------------------------
// CSR build + aggregate + segment max + misc
// ---------------------------------------------------------------------------
__global__ void count_k(const int* __restrict__ dst, int* __restrict__ cnt, int E)
{
    int e = blockIdx.x * 256 + threadIdx.x;
    if (e < E) atomicAdd(&cnt[dst[e]], 1);
}

__global__ void scan_csr(const int* __restrict__ cnt, int n, int* __restrict__ indp, int* __restrict__ curs)
{
    __shared__ int wsum[16];
    __shared__ int carry_s;
    const int tid = threadIdx.x, lane = tid & 63, w = tid >> 6;
    if (tid == 0) carry_s = 0;
    __syncthreads();
    for (int base = 0; base < n; base += 1024) {
        const int i = base + tid;
        const int v = (i < n) ? cnt[i] : 0;
        int s = v;
        #pragma unroll
        for (int o = 1; o < 64; o <<= 1) { int t = __shfl_up(s, o); if (lane >= o) s += t; }
        if (lane == 63) wsum[w] = s;
        __syncthreads();
        if (w == 0 && lane < 16) {
            int ws2 = wsum[lane];
            #pragma unroll
            for (int o = 1; o < 16; o <<= 1) { int t = __shfl_up(ws2, o); if (lane >= o) ws2 += t; }
            wsum[lane] = ws2;
        }
        __syncthreads();
        const int carry = carry_s;
        const int woff  = (w == 0) ? 0 : wsum[w - 1];
        if (i < n) { const int excl = carry + woff + s - v; indp[i] = excl; curs[i] = excl; }
        __syncthreads();
        if (tid == 0) carry_s = carry + wsum[15];
        __syncthreads();
    }
    if (threadIdx.x == 0) indp[n] = carry_s;
}

__global__ void fill_k(const int* __restrict__ src, const int* __restrict__ dst,
                       int* __restrict__ curs, int* __restrict__ esrc, int E)
{
    int e = blockIdx.x * 256 + threadIdx.x;
    if (e < E) { int p = atomicAdd(&curs[dst[e]], 1); esrc[p] = src[e]; }
}

__global__ void sage_agg(const US* __restrict__ z, const int* __restrict__ indp,
                         const int* __restrict__ esrc, US* __restrict__ agg, int n)
{
    const int w = blockIdx.x * 4 + (threadIdx.x >> 6);
    const int lane = threadIdx.x & 63;
    if (w >= n) return;
    const int beg = indp[w], end = indp[w + 1];
    float acc = 0.f;
    int j = beg;
    for (; j + 4 <= end; j += 4) {
        const int s0 = esrc[j], s1 = esrc[j + 1], s2 = esrc[j + 2], s3 = esrc[j + 3];
        const float v0 = bf2f(z[(size_t)s0 * 64 + lane]);
        const float v1 = bf2f(z[(size_t)s1 * 64 + lane]);
        const float v2 = bf2f(z[(size_t)s2 * 64 + lane]);
        const float v3 = bf2f(z[(size_t)s3 * 64 + lane]);
        acc += (v0 + v1) + (v2 + v3);
    }
    for (; j < end; ++j) acc += bf2f(z[(size_t)esrc[j] * 64 + lane]);
    const float d = (float)(end - beg);
    agg[(size_t)w * 64 + lane] = f2bf(acc / fmaxf(d, 1.0f));
}

__global__ void segmax_k(const US* __restrict__ z, const int* __restrict__ batch,
                         UI* __restrict__ enc, int n, int per)
{
    const int w = blockIdx.x * 4 + (threadIdx.x >> 6);
    const int lane = threadIdx.x & 63;
    const int start = w * per;
    if (start >= n) return;
    const int end = (start + per < n) ? start + per : n;
    int g = batch[start];
    float m = -3.0e38f;
    for (int i = start; i < end; ++i) {
        const int b = batch[i];
        if (b != g) { atomicMax(&enc[(size_t)g * 64 + lane], encf(m)); g = b; m = -3.0e38f; }
        m = fmaxf(m, bf2f(z[(size_t)i * 64 + lane]));
    }
    atomicMax(&enc[(size_t)g * 64 + lane], encf(m));
}

__global__ void decode_ge(const UI* __restrict__ enc, US* __restrict__ geb)
{
    const int i = blockIdx.x * 256 + threadIdx.x;
    if (i < 4096) geb[i] = f2bf(decf(enc[i]));
}

__global__ void copy_bf2f(const US* __restrict__ z, float* __restrict__ o, long n)
{
    long i = (long)blockIdx.x * blockDim.x + threadIdx.x;
    const long stride = (long)gridDim.x * blockDim.x;
    for (; i < n; i += stride) o[i] = bf2f(z[i]);
}

// ---------------------------------------------------------------------------
extern "C" void kernel_launch(void* const* d_in, const int* in_sizes, int n_in,
                              void* d_out, int out_size, void* d_ws, size_t ws_size,
                              hipStream_t stream)
{
    (void)in_sizes; (void)n_in; (void)out_size; (void)ws_size;

    const float* x      = (const float*)d_in[0];
    const int*   batch  = (const int*)d_in[1];
    const int*   eidx   = (const int*)d_in[2];
    const int*   srcq   = (const int*)d_in[3];
    const int*   dstq   = (const int*)d_in[4];
    const float* em_in_b   = (const float*)d_in[6];
    const float* em_hid_b  = (const float*)d_in[8];
    const float* em_out_b  = (const float*)d_in[10];
    const float* em_proj_b = (const float*)d_in[12];
    const float* rho_in_b  = (const float*)d_in[14];
    const float* rho_hid_b = (const float*)d_in[16];
    const float* rho_out_b = (const float*)d_in[18];
    const float* rho_proj_b= (const float*)d_in[20];
    const float* c_ll_W[3] = {(const float*)d_in[21], (const float*)d_in[24], (const float*)d_in[27]};
    const float* c_ll_b[3] = {(const float*)d_in[22], (const float*)d_in[25], (const float*)d_in[28]};
    const float* c_lr_W[3] = {(const float*)d_in[23], (const float*)d_in[26], (const float*)d_in[29]};
    const float* h1_in_b   = (const float*)d_in[31];
    const float* h1_hid_b  = (const float*)d_in[33];
    const float* h1_out_b  = (const float*)d_in[35];
    const float* h1_proj_b = (const float*)d_in[37];
    const float* h2_in_b   = (const float*)d_in[39];
    const float* h2_hid_b  = (const float*)d_in[41];
    const float* h2_out_W  = (const float*)d_in[42];
    const float* h2_out_b  = (const float*)d_in[43];

    const int N = 50000, E = 1600000, Q = 500000;
    float* out = (float*)d_out;

    // ---- workspace layout ----
    char* wsb = (char*)d_ws;
    size_t off = 0;
    auto ALLOC = [&](size_t bytes) -> char* {
        char* p = wsb + off; off = (off + bytes + 255) & ~(size_t)255; return p;
    };
    US*  WB   = (US*)ALLOC((size_t)W_TOTAL * 2);
    US*  Ss   = (US*)ALLOC((size_t)N * 512 * 2);
    US*  z0   = (US*)ALLOC((size_t)N * 64 * 2);
    US*  z1   = (US*)ALLOC((size_t)N * 64 * 2);
    US*  aggB = (US*)ALLOC((size_t)N * 64 * 2);
    int* cnt  = (int*)ALLOC((size_t)N * 4);
    int* indp = (int*)ALLOC((size_t)(N + 1) * 4);
    int* curs = (int*)ALLOC((size_t)N * 4);
    int* esrc = (int*)ALLOC((size_t)E * 4);
    UI*  enc  = (UI*)ALLOC(4096 * 4);
    US*  geb  = (US*)ALLOC(4096 * 2);

    const int catOff[3] = {O_Cat1, O_Cat2, O_Cat3};

    WPrm pw; int si = 0;
    auto SEG = [&](const float* s, int o, int n, int rl, int ldd) {
        pw.s[si].src = s; pw.s[si].dst = o; pw.s[si].n = n; pw.s[si].rl = rl; pw.s[si].ldd = ldd; ++si;
    };
    SEG((const float*)d_in[5],  O_EmW1,          65536, 65536, 65536);
    SEG((const float*)d_in[11], O_EmW1 + 65536,  65536, 65536, 65536);
    SEG((const float*)d_in[7],  O_EmWh,          16384, 16384, 16384);
    SEG((const float*)d_in[9],  O_EmWo,          65536, 65536, 65536);
    SEG((const float*)d_in[13], O_RhoW1,         65536, 65536, 65536);
    SEG((const float*)d_in[19], O_RhoW1 + 65536, 65536, 65536, 65536);
    SEG((const float*)d_in[15], O_RhoWh,         16384, 16384, 16384);
    SEG((const float*)d_in[17], O_RhoWo,          8192,  8192,  8192);
    for (int i = 0; i < 3; ++i) {
        SEG(c_ll_W[i], catOff[i],      4096, 64, 128);
        SEG(c_lr_W[i], catOff[i] + 64, 4096, 64, 128);
    }
    SEG((const float*)d_in[30], O_H1W1,          24576, 24576, 24576);
    SEG((const float*)d_in[36], O_H1W1 + 24576,  24576, 24576, 24576);
    SEG((const float*)d_in[32], O_H1Wh,          16384, 16384, 16384);
    SEG((const float*)d_in[34], O_H1Wo,          16384, 16384, 16384);
    SEG((const float*)d_in[38], O_H2W1,          16384, 16384, 16384);
    SEG((const float*)d_in[40], O_H2Wh,          16384, 16384, 16384);
    prep_w<<<dim3(20), dim3(256), 0, stream>>>(pw, WB);

    // ---- CSR build ----
    hipMemsetAsync(cnt, 0, (size_t)N * 4, stream);
    count_k<<<dim3((E + 255) / 256), dim3(256), 0, stream>>>(eidx + E, cnt, E);
    scan_csr<<<dim3(1), dim3(1024), 0, stream>>>(cnt, N, indp, curs);
    fill_k<<<dim3((E + 255) / 256), dim3(256), 0, stream>>>(eidx, eidx + E, curs, esrc, E);

    // ---- Embedder + rho ----
    embed_fused<<<dim3(3125), dim3(1024), 0, stream>>>(x, WB, em_in_b, em_proj_b, em_hid_b, em_out_b, Ss);
    rho_fused<<<dim3((N + 63) / 64), dim3(512), 0, stream>>>(Ss, WB, rho_in_b, rho_proj_b, rho_hid_b, rho_out_b, z0, N);

    // ---- 3x SAGE residual ----
    US* zin = z0; US* zout = z1;
    for (int ci = 0; ci < 3; ++ci) {
        sage_agg<<<dim3((N + 3) / 4), dim3(256), 0, stream>>>(zin, indp, esrc, aggB, N);
        sage_gemm<<<dim3((N + 127) / 128), dim3(256), 0, stream>>>(zin, aggB, WB + catOff[ci], c_ll_b[ci], zout, N);
        US* t = zin; zin = zout; zout = t;
    }
    US* zf = zin;

    // ---- graph max-pool ----
    hipMemsetAsync(enc, 0, 4096 * 4, stream);
    segmax_k<<<dim3((N + 511) / 512), dim3(256), 0, stream>>>(zf, batch, enc, N, 128);
    decode_ge<<<dim3(16), dim3(256), 0, stream>>>(enc, geb);

    // ---- node_embeddings output ----
    copy_bf2f<<<dim3(2048), dim3(256), 0, stream>>>(zf, out, (long)N * 64);

    // ---- fused heads (128 queries/block, both sides, 16 waves/block) ----
    head_fused<<<dim3((Q + 127) / 128), dim3(1024), 0, stream>>>(
        srcq, dstq, batch, zf, geb, WB,
        h1_in_b, h1_proj_b, h1_hid_b, h1_out_b, h2_in_b, h2_hid_b, h2_out_W, h2_out_b,
        out + (size_t)N * 64, out + (size_t)N * 64 + 2 * (size_t)Q, Q);
}

// Round 9
// 2004.201 us; speedup vs baseline: 1.0850x; 1.0850x over previous
//
#include <hip/hip_runtime.h>

typedef unsigned short US;
typedef unsigned int   UI;
typedef short  short8 __attribute__((ext_vector_type(8)));
typedef US     u16x8  __attribute__((ext_vector_type(8)));
typedef float  f32x4  __attribute__((ext_vector_type(4)));

#define DEVI __device__ __forceinline__

DEVI float bf2f(US u){ UI i = ((UI)u) << 16; float f; __builtin_memcpy(&f, &i, 4); return f; }
DEVI US f2bf(float x){ UI i; __builtin_memcpy(&i, &x, 4); UI r = (i + 0x7FFFu + ((i >> 16) & 1u)) >> 16; return (US)r; }
// erf via Abramowitz-Stegun 7.1.26 (|eps| <= 1.5e-7; exact at bf16 precision)
DEVI float erf_fast(float z){
    float az = fabsf(z);
    float t = 1.0f / fmaf(0.3275911f, az, 1.0f);
    float p = t * fmaf(t, fmaf(t, fmaf(t, fmaf(t, 1.061405429f, -1.453152027f),
                 1.421413741f), -0.284496736f), 0.254829592f);
    float e = __expf(-az * az);
    float er = fmaf(-p, e, 1.0f);
    return copysignf(er, z);
}
DEVI float gelu_f(float x){ return 0.5f * x * (1.0f + erf_fast(x * 0.70710678118654752f)); }
DEVI UI encf(float f){ UI u; __builtin_memcpy(&u, &f, 4); return (u & 0x80000000u) ? ~u : (u | 0x80000000u); }
DEVI float decf(UI u){ UI b = (u & 0x80000000u) ? (u ^ 0x80000000u) : ~u; float f; __builtin_memcpy(&f, &b, 4); return f; }
DEVI int swz(int r, int c, int ld){ int i = r * ld + c; return i ^ ((r & 7) << 3); }

// bf16 weight-buffer offsets (elements)
enum : int { O_EmW1 = 0, O_EmWh = 131072, O_EmWo = 147456, O_RhoW1 = 212992,
             O_RhoWh = 344064, O_RhoWo = 360448, O_Cat1 = 368640, O_Cat2 = 376832,
             O_Cat3 = 385024, O_H1W1 = 393216, O_H1Wh = 442368, O_H1Wo = 458752,
             O_H2W1 = 475136, O_H2Wh = 491520, W_TOTAL = 507904 };

// ---------------------------------------------------------------------------
// Double-buffered W-streaming stage: NTHR threads, wave tile 16 rows x
// NT*16 cols (wc = (w&1) picks col group). W slab [NT*32 x 64] x2 buffers.
// ONE barrier per kc: [bar; prefetch W(kc+1); MFMA slab kc&1; write slab
// (kc+1)&1]. The kc-top bar also makes prior-stage epilogue T1 writes
// visible (cross-wave column halves). Trailing bar protects Wb reuse.
// ---------------------------------------------------------------------------
template<int NT, int NKC, int NTHR>
DEVI void stageWD(const US* __restrict__ Wg, int Kw, const US* __restrict__ A, int lda,
                  int ab0, int ab1, int ab2, int arow0, US* Wb, int tid, f32x4 (&acc)[NT])
{
    const int lane = tid & 63;
    const int wc = (tid >> 6) & 1;
    constexpr int SLAB = NT * 32 * 64;
    #pragma unroll
    for (int n = 0; n < NT; ++n) acc[n] = (f32x4){0.f, 0.f, 0.f, 0.f};
    constexpr int J = (NT * 256) / NTHR;
    u16x8 wreg[J];
    #pragma unroll
    for (int j = 0; j < J; ++j) {
        const int c = tid + NTHR * j;
        wreg[j] = *(const u16x8*)(Wg + (size_t)(c >> 3) * Kw + (c & 7) * 8);
    }
    #pragma unroll
    for (int j = 0; j < J; ++j) {
        const int c = tid + NTHR * j;
        *(u16x8*)&Wb[swz(c >> 3, (c & 7) * 8, 64)] = wreg[j];
    }
    #pragma unroll
    for (int kc = 0; kc < NKC; ++kc) {
        __syncthreads();            // slab kc&1 visible; prior reads done
        if (kc + 1 < NKC) {
            #pragma unroll
            for (int j = 0; j < J; ++j) {
                const int c = tid + NTHR * j;
                wreg[j] = *(const u16x8*)(Wg + (size_t)(c >> 3) * Kw + (kc + 1) * 64 + (c & 7) * 8);
            }
        }
        const int ab = (kc == 0) ? ab0 : ((kc == 1) ? ab1 : ab2);
        const int bufr = (kc & 1) * SLAB;
        #pragma unroll
        for (int sub = 0; sub < 2; ++sub) {
            const int kk = sub * 32 + ((lane >> 4) << 3);
            short8 a = *(const short8*)&A[swz(arow0 + (lane & 15), ab + kk, lda)];
            #pragma unroll
            for (int n = 0; n < NT; ++n) {
                short8 b = *(const short8*)&Wb[bufr + swz(wc * (NT * 16) + n * 16 + (lane & 15), kk, 64)];
                acc[n] = __builtin_amdgcn_mfma_f32_16x16x32_bf16(a, b, acc[n], 0, 0, 0);
            }
        }
        if (kc + 1 < NKC) {
            const int bufw = ((kc + 1) & 1) * SLAB;
            #pragma unroll
            for (int j = 0; j < J; ++j) {
                const int c = tid + NTHR * j;
                *(u16x8*)&Wb[bufw + swz(c >> 3, (c & 7) * 8, 64)] = wreg[j];
            }
        }
    }
    __syncthreads();                // all Wb reads done before reuse
}

// ---------------------------------------------------------------------------
// Fused embedder: 128 point-rows (16 nodes) per block, 1024 threads (16 waves).
// S1 custom (A+W streamed); S2 + merged S3 use stageWD.
// LDS: T1 64KB + Wb 64KB + As 16KB = 144.5KB -> 1 block/CU, 16 waves.
// ---------------------------------------------------------------------------
__global__ __launch_bounds__(1024, 4)
void embed_fused(const float* __restrict__ x, const US* __restrict__ WB,
                 const float* __restrict__ b_in, const float* __restrict__ b_proj,
                 const float* __restrict__ b_hid, const float* __restrict__ b_out,
                 US* __restrict__ Ss)
{
    __shared__ __align__(16) US T1[128 * 256];
    __shared__ __align__(16) US Wb[2 * 16384];
    __shared__ __align__(16) US As[128 * 64];
    const int tid = threadIdx.x, lane = tid & 63, w = tid >> 6;
    const int wr = w >> 1, wc = w & 1;
    const int grow0 = blockIdx.x * 128;
    const int row0 = wr * 16 + ((lane >> 4) << 2);

    { // ---- stage 1: out 256, K=512 (8 kc) ----
        f32x4 acc[8];
        #pragma unroll
        for (int n = 0; n < 8; ++n) acc[n] = (f32x4){0.f, 0.f, 0.f, 0.f};
        const float* xr = x + (size_t)(grow0 + (tid >> 3)) * 512 + (tid & 7) * 8;
        float4 a0, a1;
        u16x8 wreg[2];
        auto loadA = [&](int kc) { a0 = *(const float4*)(xr + kc * 64); a1 = *(const float4*)(xr + kc * 64 + 4); };
        auto loadW = [&](int kc) {
            #pragma unroll
            for (int j = 0; j < 2; ++j) {
                const int c = tid + 1024 * j;
                wreg[j] = *(const u16x8*)(WB + O_EmW1 + (size_t)(c >> 3) * 512 + kc * 64 + (c & 7) * 8);
            }
        };
        loadA(0); loadW(0);
        for (int kc = 0; kc < 8; ++kc) {
            __syncthreads();
            {
                u16x8 v;
                v[0] = f2bf(a0.x); v[1] = f2bf(a0.y); v[2] = f2bf(a0.z); v[3] = f2bf(a0.w);
                v[4] = f2bf(a1.x); v[5] = f2bf(a1.y); v[6] = f2bf(a1.z); v[7] = f2bf(a1.w);
                *(u16x8*)&As[swz(tid >> 3, (tid & 7) * 8, 64)] = v;
                #pragma unroll
                for (int j = 0; j < 2; ++j) {
                    const int c = tid + 1024 * j;
                    *(u16x8*)&Wb[swz(c >> 3, (c & 7) * 8, 64)] = wreg[j];
                }
            }
            __syncthreads();
            if (kc < 7) { loadA(kc + 1); loadW(kc + 1); }
            #pragma unroll
            for (int sub = 0; sub < 2; ++sub) {
                const int kk = sub * 32 + ((lane >> 4) << 3);
                short8 a = *(const short8*)&As[swz(wr * 16 + (lane & 15), kk, 64)];
                #pragma unroll
                for (int n = 0; n < 8; ++n) {
                    short8 b = *(const short8*)&Wb[swz(wc * 128 + n * 16 + (lane & 15), kk, 64)];
                    acc[n] = __builtin_amdgcn_mfma_f32_16x16x32_bf16(a, b, acc[n], 0, 0, 0);
                }
            }
        }
        __syncthreads();
        #pragma unroll
        for (int n = 0; n < 8; ++n) {
            const int col = wc * 128 + n * 16 + (lane & 15);
            const float bv = (col < 128) ? b_in[col] : b_proj[col - 128];
            #pragma unroll
            for (int r = 0; r < 4; ++r) {
                float v = acc[n][r] + bv;
                if (col < 128) v = gelu_f(v);
                T1[swz(row0 + r, col, 256)] = f2bf(v);
            }
        }
    }
    { // ---- stage 2: U = s + gelu(t1@Wh+bh) -> T1 lo ----
        f32x4 acc[4];
        stageWD<4, 2, 1024>(WB + O_EmWh, 128, T1, 256, 0, 64, 0, wr * 16, Wb, tid, acc);
        #pragma unroll
        for (int n = 0; n < 4; ++n) {
            const int col = wc * 64 + n * 16 + (lane & 15);
            const float bv = b_hid[col];
            #pragma unroll
            for (int r = 0; r < 4; ++r) {
                const float sv = bf2f(T1[swz(row0 + r, 128 + col, 256)]);
                T1[swz(row0 + r, col, 256)] = f2bf(gelu_f(acc[n][r] + bv) + sv);
            }
        }
    }
    // ---- stage 3: 2 merged passes (NT=8, 256 cols each), sum8 epilogue ----
    for (int p2 = 0; p2 < 2; ++p2) {
        f32x4 acc[8];
        stageWD<8, 2, 1024>(WB + O_EmWo + (size_t)(p2 * 256) * 128, 128, T1, 256, 0, 64, 0, wr * 16, Wb, tid, acc);
        #pragma unroll
        for (int n = 0; n < 8; ++n) {
            const int col = wc * 128 + n * 16 + (lane & 15);
            const float bv = b_out[p2 * 256 + col];
            float s = 0.f;
            #pragma unroll
            for (int r = 0; r < 4; ++r) s += gelu_f(acc[n][r] + bv);
            s += __shfl_xor(s, 16);
            if (((lane >> 4) & 1) == 0) {
                const int node = (grow0 >> 3) + wr * 2 + (lane >> 5);
                Ss[(size_t)node * 512 + p2 * 256 + col] = f2bf(s);
            }
        }
    }
}

// ---------------------------------------------------------------------------
// Fused rho: 64 nodes per block, 512 threads. S2/S3 use stageWD.
// ---------------------------------------------------------------------------
__global__ __launch_bounds__(512, 2)
void rho_fused(const US* __restrict__ Ss, const US* __restrict__ WB,
               const float* __restrict__ b_in, const float* __restrict__ b_proj,
               const float* __restrict__ b_hid, const float* __restrict__ b_out,
               US* __restrict__ zo, int N)
{
    __shared__ __align__(16) US T1[64 * 256];
    __shared__ __align__(16) US Wb[256 * 64];
    __shared__ __align__(16) US As[64 * 64];
    const int tid = threadIdx.x, lane = tid & 63, w = tid >> 6;
    const int wr = w >> 1, wc = w & 1;
    const int grow0 = blockIdx.x * 64;
    const int row0 = wr * 16 + ((lane >> 4) << 2);

    { // ---- stage 1: out 256, K=512 ----
        f32x4 acc[8];
        #pragma unroll
        for (int n = 0; n < 8; ++n) acc[n] = (f32x4){0.f, 0.f, 0.f, 0.f};
        int arow = grow0 + (tid >> 3); if (arow >= N) arow = N - 1;
        const US* srow = Ss + (size_t)arow * 512 + (tid & 7) * 8;
        u16x8 areg, wreg[4];
        auto loadA = [&](int kc) { areg = *(const u16x8*)(srow + kc * 64); };
        auto loadW = [&](int kc) {
            #pragma unroll
            for (int j = 0; j < 4; ++j) {
                const int c = tid + 512 * j;
                wreg[j] = *(const u16x8*)(WB + O_RhoW1 + (size_t)(c >> 3) * 512 + kc * 64 + (c & 7) * 8);
            }
        };
        loadA(0); loadW(0);
        for (int kc = 0; kc < 8; ++kc) {
            __syncthreads();
            *(u16x8*)&As[swz(tid >> 3, (tid & 7) * 8, 64)] = areg;
            #pragma unroll
            for (int j = 0; j < 4; ++j) {
                const int c = tid + 512 * j;
                *(u16x8*)&Wb[swz(c >> 3, (c & 7) * 8, 64)] = wreg[j];
            }
            __syncthreads();
            if (kc < 7) { loadA(kc + 1); loadW(kc + 1); }
            #pragma unroll
            for (int sub = 0; sub < 2; ++sub) {
                const int kk = sub * 32 + ((lane >> 4) << 3);
                short8 a = *(const short8*)&As[swz(wr * 16 + (lane & 15), kk, 64)];
                #pragma unroll
                for (int n = 0; n < 8; ++n) {
                    short8 b = *(const short8*)&Wb[swz(wc * 128 + n * 16 + (lane & 15), kk, 64)];
                    acc[n] = __builtin_amdgcn_mfma_f32_16x16x32_bf16(a, b, acc[n], 0, 0, 0);
                }
            }
        }
        __syncthreads();
        #pragma unroll
        for (int n = 0; n < 8; ++n) {
            const int col = wc * 128 + n * 16 + (lane & 15);
            const float bv = (col < 128) ? b_in[col] : b_proj[col - 128];
            #pragma unroll
            for (int r = 0; r < 4; ++r) {
                float v = acc[n][r] + bv;
                if (col < 128) v = gelu_f(v);
                T1[swz(row0 + r, col, 256)] = f2bf(v);
            }
        }
    }
    { // ---- stage 2: RU -> T1 lo ----
        f32x4 acc[4];
        stageWD<4, 2, 512>(WB + O_RhoWh, 128, T1, 256, 0, 64, 0, wr * 16, Wb, tid, acc);
        #pragma unroll
        for (int n = 0; n < 4; ++n) {
            const int col = wc * 64 + n * 16 + (lane & 15);
            const float bv = b_hid[col];
            #pragma unroll
            for (int r = 0; r < 4; ++r) {
                const float sv = bf2f(T1[swz(row0 + r, 128 + col, 256)]);
                T1[swz(row0 + r, col, 256)] = f2bf(gelu_f(acc[n][r] + bv) + sv);
            }
        }
    }
    { // ---- stage 3: out 64 ----
        f32x4 acc[2];
        stageWD<2, 2, 512>(WB + O_RhoWo, 128, T1, 256, 0, 64, 0, wr * 16, Wb, tid, acc);
        #pragma unroll
        for (int n = 0; n < 2; ++n) {
            const int col = wc * 32 + n * 16 + (lane & 15);
            const float bv = b_out[col];
            #pragma unroll
            for (int r = 0; r < 4; ++r) {
                const int node = grow0 + row0 + r;
                if (node < N) zo[(size_t)node * 64 + col] = f2bf(acc[n][r] + bv);
            }
        }
    }
}

// ---------------------------------------------------------------------------
// Fused head v5 = R5 geometry (measured best: LDS A0, acc[4], VGPR 64, no
// spill) + double-buffered stageWD (1 bar/kc instead of 2).
// 64 queries/block, 1024 threads (16 waves), both sides share every W pass.
// T1 rows 0-63 = xy, 64-127 = yx; wave: wr=w>>1 rows, wc=w&1 cols.
// LDS: A0 24KB + T1 64KB + Wb 32KB = 120.5KB -> 1 block/CU, 16 waves.
// ---------------------------------------------------------------------------
__global__ __launch_bounds__(1024, 4)
void head_fused(const int* __restrict__ srcq, const int* __restrict__ dstq,
                const int* __restrict__ batch, const US* __restrict__ z,
                const US* __restrict__ geb, const US* __restrict__ WB,
                const float* __restrict__ b1_in, const float* __restrict__ b1_proj,
                const float* __restrict__ b1_hid, const float* __restrict__ b1_out,
                const float* __restrict__ b2_in, const float* __restrict__ b2_hid,
                const float* __restrict__ w2_out, const float* __restrict__ b2_out,
                float* __restrict__ outH, float* __restrict__ outXY, int Q)
{
    __shared__ __align__(16) US A0[64 * 192];
    __shared__ __align__(16) US T1[128 * 256];
    __shared__ __align__(16) US Wb[2 * 8192];
    __shared__ float wout_s[128];
    const int tid = threadIdx.x, lane = tid & 63, w = tid >> 6;
    const int wr = w >> 1, wc = w & 1;
    const int row0 = wr * 16 + ((lane >> 4) << 2);
    const int q0 = blockIdx.x * 64;
    // side-dependent S1 K-chunk order: side0 {0,64,128}, side1 {64,0,128}
    const int s1a = (wr < 4) ? 0 : 64;
    const int s1b = (wr < 4) ? 64 : 0;
    const int arowS1 = (wr & 3) * 16;
    { // gather: 8 threads per query row (512 threads active)
        if (tid < 512) {
            const int r = tid >> 3, h = tid & 7;
            const int q = q0 + r;
            const int qc = (q < Q) ? q : (Q - 1);
            const int s = srcq[qc], d = dstq[qc];
            const int g = batch[s];
            *(u16x8*)&A0[swz(r, h * 8, 192)]       = *(const u16x8*)(z + (size_t)s * 64 + h * 8);
            *(u16x8*)&A0[swz(r, 64 + h * 8, 192)]  = *(const u16x8*)(z + (size_t)d * 64 + h * 8);
            *(u16x8*)&A0[swz(r, 128 + h * 8, 192)] = *(const u16x8*)(geb + (size_t)g * 64 + h * 8);
        }
        if (tid < 128) wout_s[tid] = w2_out[tid];
    }
    __syncthreads();
    { // xy output (f32): 64 rows x 48 float4 = 3072
        #pragma unroll
        for (int jj = 0; jj < 3; ++jj) {
            const int f = tid + 1024 * jj;
            const int row = f / 48;
            const int c4 = (f - row * 48) * 4;
            if (q0 + row < Q) {
                const US* p = &A0[swz(row, c4, 192)];
                float4 o;
                o.x = bf2f(p[0]); o.y = bf2f(p[1]); o.z = bf2f(p[2]); o.w = bf2f(p[3]);
                *(float4*)&outXY[(size_t)(q0 + row) * 192 + c4] = o;
            }
        }
    }
    f32x4 acc[4];
    // S1p0: t1 = gelu(A0@W1in + b) -> T1 lo (both sides)
    stageWD<4, 3, 1024>(WB + O_H1W1, 192, A0, 192, s1a, s1b, 128, arowS1, Wb, tid, acc);
    #pragma unroll
    for (int n = 0; n < 4; ++n) {
        const int col = wc * 64 + n * 16 + (lane & 15);
        const float bv = b1_in[col];
        #pragma unroll
        for (int r = 0; r < 4; ++r)
            T1[swz(row0 + r, col, 256)] = f2bf(gelu_f(acc[n][r] + bv));
    }
    // S1p1: s1 = A0@Wproj + b -> T1 hi
    stageWD<4, 3, 1024>(WB + O_H1W1 + 128 * 192, 192, A0, 192, s1a, s1b, 128, arowS1, Wb, tid, acc);
    #pragma unroll
    for (int n = 0; n < 4; ++n) {
        const int col = wc * 64 + n * 16 + (lane & 15);
        const float bv = b1_proj[col];
        #pragma unroll
        for (int r = 0; r < 4; ++r)
            T1[swz(row0 + r, 128 + col, 256)] = f2bf(acc[n][r] + bv);
    }
    // S2: U = s1 + gelu(t1@Wh + bh) -> T1 lo
    stageWD<4, 2, 1024>(WB + O_H1Wh, 128, T1, 256, 0, 64, 0, wr * 16, Wb, tid, acc);
    #pragma unroll
    for (int n = 0; n < 4; ++n) {
        const int col = wc * 64 + n * 16 + (lane & 15);
        const float bv = b1_hid[col];
        #pragma unroll
        for (int r = 0; r < 4; ++r) {
            const float sv = bf2f(T1[swz(row0 + r, 128 + col, 256)]);
            T1[swz(row0 + r, col, 256)] = f2bf(gelu_f(acc[n][r] + bv) + sv);
        }
    }
    // S3: T = relu(U@Wo + bo) -> T1 hi
    stageWD<4, 2, 1024>(WB + O_H1Wo, 128, T1, 256, 0, 64, 0, wr * 16, Wb, tid, acc);
    #pragma unroll
    for (int n = 0; n < 4; ++n) {
        const int col = wc * 64 + n * 16 + (lane & 15);
        const float bv = b1_out[col];
        #pragma unroll
        for (int r = 0; r < 4; ++r)
            T1[swz(row0 + r, 128 + col, 256)] = f2bf(fmaxf(acc[n][r] + bv, 0.f));
    }
    // S4: B1 = gelu(T@W2 + b2) -> T1 lo (A = T1 hi)
    stageWD<4, 2, 1024>(WB + O_H2W1, 128, T1, 256, 128, 192, 0, wr * 16, Wb, tid, acc);
    #pragma unroll
    for (int n = 0; n < 4; ++n) {
        const int col = wc * 64 + n * 16 + (lane & 15);
        const float bv = b2_in[col];
        #pragma unroll
        for (int r = 0; r < 4; ++r)
            T1[swz(row0 + r, col, 256)] = f2bf(gelu_f(acc[n][r] + bv));
    }
    // S5: U2 = T + gelu(B1@Wh2 + bh2) -> T1 lo
    stageWD<4, 2, 1024>(WB + O_H2Wh, 128, T1, 256, 0, 64, 0, wr * 16, Wb, tid, acc);
    #pragma unroll
    for (int n = 0; n < 4; ++n) {
        const int col = wc * 64 + n * 16 + (lane & 15);
        const float bv = b2_hid[col];
        #pragma unroll
        for (int r = 0; r < 4; ++r) {
            const float tv = bf2f(T1[swz(row0 + r, 128 + col, 256)]);
            T1[swz(row0 + r, col, 256)] = f2bf(gelu_f(acc[n][r] + bv) + tv);
        }
    }
    __syncthreads();   // U2 visible before dot (cross-wave rows)
    // S6: scalar head: 128 rows x 8 threads, 16 cols each
    {
        const int r = tid >> 3, h = tid & 7;   // r 0..127: side = r>>6
        float a = 0.f;
        u16x8 v0 = *(const u16x8*)&T1[swz(r, h * 16, 256)];
        u16x8 v1 = *(const u16x8*)&T1[swz(r, h * 16 + 8, 256)];
        #pragma unroll
        for (int e = 0; e < 8; ++e) {
            a += bf2f(v0[e]) * wout_s[h * 16 + e];
            a += bf2f(v1[e]) * wout_s[h * 16 + 8 + e];
        }
        a += __shfl_xor(a, 4);
        a += __shfl_xor(a, 2);
        a += __shfl_xor(a, 1);
        const int q = q0 + (r & 63);
        if ((lane & 7) == 0 && q < Q) outH[(size_t)(r >> 6) * Q + q] = a + b2_out[0];
    }
}

// ---------------------------------------------------------------------------
// SAGE layer: zout = zin + gelu( [agg|zin] @ Wcat^T + bl ), K=128, out 64
// ---------------------------------------------------------------------------
__global__ __launch_bounds__(256, 2)
void sage_gemm(const US* __restrict__ zin, const US* __restrict__ agg,
               const US* __restrict__ Wc, const float* __restrict__ bias,
               US* __restrict__ zout, int N)
{
    __shared__ __align__(16) US As[128 * 128];
    __shared__ __align__(16) US Ws[64 * 128];
    const int tid = threadIdx.x, lane = tid & 63, w = tid >> 6;
    const int grow0 = blockIdx.x * 128;
    {
        const int r = tid >> 1, h = tid & 1;
        int row = grow0 + r; if (row >= N) row = N - 1;
        const US* src = h ? (zin + (size_t)row * 64) : (agg + (size_t)row * 64);
        #pragma unroll
        for (int j = 0; j < 8; ++j)
            *(u16x8*)&As[swz(r, h * 64 + 8 * j, 128)] = *(const u16x8*)(src + 8 * j);
    }
    #pragma unroll
    for (int j = 0; j < 4; ++j) {
        const int c = tid + 256 * j;
        *(u16x8*)&Ws[swz(c >> 4, (c & 15) * 8, 128)] =
            *(const u16x8*)(Wc + (size_t)(c >> 4) * 128 + (c & 15) * 8);
    }
    __syncthreads();
    const int rbw = w * 32;
    f32x4 acc[2][4];
    #pragma unroll
    for (int m = 0; m < 2; ++m)
        #pragma unroll
        for (int n = 0; n < 4; ++n) acc[m][n] = (f32x4){0.f, 0.f, 0.f, 0.f};
    #pragma unroll
    for (int kc = 0; kc < 2; ++kc)
        #pragma unroll
        for (int sub = 0; sub < 2; ++sub) {
            const int kk = kc * 64 + sub * 32 + ((lane >> 4) << 3);
            short8 a[2], b[4];
            #pragma unroll
            for (int m = 0; m < 2; ++m) a[m] = *(const short8*)&As[swz(rbw + m * 16 + (lane & 15), kk, 128)];
            #pragma unroll
            for (int n = 0; n < 4; ++n) b[n] = *(const short8*)&Ws[swz(n * 16 + (lane & 15), kk, 128)];
            #pragma unroll
            for (int m = 0; m < 2; ++m)
                #pragma unroll
                for (int n = 0; n < 4; ++n)
                    acc[m][n] = __builtin_amdgcn_mfma_f32_16x16x32_bf16(a[m], b[n], acc[m][n], 0, 0, 0);
        }
    #pragma unroll
    for (int m = 0; m < 2; ++m) {
        const int row0 = rbw + m * 16 + ((lane >> 4) << 2);
        #pragma unroll
        for (int n = 0; n < 4; ++n) {
            const int col = n * 16 + (lane & 15);
            const float bv = bias[col];
            #pragma unroll
            for (int r = 0; r < 4; ++r) {
                const int node = grow0 + row0 + r;
                if (node < N) {
                    const float v = gelu_f(acc[m][n][r] + bv) + bf2f(zin[(size_t)node * 64 + col]);
                    zout[(size_t)node * 64 + col] = f2bf(v);
                }
            }
        }
    }
}

// ---------------------------------------------------------------------------
// Weight prep (f32 -> bf16, strided stacking)
// ---------------------------------------------------------------------------
struct WSeg { const float* src; int dst; int n; int rl; int ldd; };
struct WPrm { WSeg s[20]; };

__global__ void prep_w(WPrm p, US* __restrict__ wb)
{
    WSeg sg = p.s[blockIdx.x];
    for (int i = threadIdx.x; i < sg.n; i += 256) {
        const int idx = sg.dst + (i / sg.rl) * sg.ldd + (i % sg.rl);
        wb[idx] = f2bf(sg.src[i]);
    }
}

// ---------------------------------------------------------------------------
// CSR build + aggregate + segment max + misc
// ---------------------------------------------------------------------------
__global__ void count_k(const int* __restrict__ dst, int* __restrict__ cnt, int E)
{
    int e = blockIdx.x * 256 + threadIdx.x;
    if (e < E) atomicAdd(&cnt[dst[e]], 1);
}

__global__ void scan_csr(const int* __restrict__ cnt, int n, int* __restrict__ indp, int* __restrict__ curs)
{
    __shared__ int wsum[16];
    __shared__ int carry_s;
    const int tid = threadIdx.x, lane = tid & 63, w = tid >> 6;
    if (tid == 0) carry_s = 0;
    __syncthreads();
    for (int base = 0; base < n; base += 1024) {
        const int i = base + tid;
        const int v = (i < n) ? cnt[i] : 0;
        int s = v;
        #pragma unroll
        for (int o = 1; o < 64; o <<= 1) { int t = __shfl_up(s, o); if (lane >= o) s += t; }
        if (lane == 63) wsum[w] = s;
        __syncthreads();
        if (w == 0 && lane < 16) {
            int ws2 = wsum[lane];
            #pragma unroll
            for (int o = 1; o < 16; o <<= 1) { int t = __shfl_up(ws2, o); if (lane >= o) ws2 += t; }
            wsum[lane] = ws2;
        }
        __syncthreads();
        const int carry = carry_s;
        const int woff  = (w == 0) ? 0 : wsum[w - 1];
        if (i < n) { const int excl = carry + woff + s - v; indp[i] = excl; curs[i] = excl; }
        __syncthreads();
        if (tid == 0) carry_s = carry + wsum[15];
        __syncthreads();
    }
    if (threadIdx.x == 0) indp[n] = carry_s;
}

__global__ void fill_k(const int* __restrict__ src, const int* __restrict__ dst,
                       int* __restrict__ curs, int* __restrict__ esrc, int E)
{
    int e = blockIdx.x * 256 + threadIdx.x;
    if (e < E) { int p = atomicAdd(&curs[dst[e]], 1); esrc[p] = src[e]; }
}

__global__ void sage_agg(const US* __restrict__ z, const int* __restrict__ indp,
                         const int* __restrict__ esrc, US* __restrict__ agg, int n)
{
    const int w = blockIdx.x * 4 + (threadIdx.x >> 6);
    const int lane = threadIdx.x & 63;
    if (w >= n) return;
    const int beg = indp[w], end = indp[w + 1];
    float acc = 0.f;
    int j = beg;
    for (; j + 4 <= end; j += 4) {
        const int s0 = esrc[j], s1 = esrc[j + 1], s2 = esrc[j + 2], s3 = esrc[j + 3];
        const float v0 = bf2f(z[(size_t)s0 * 64 + lane]);
        const float v1 = bf2f(z[(size_t)s1 * 64 + lane]);
        const float v2 = bf2f(z[(size_t)s2 * 64 + lane]);
        const float v3 = bf2f(z[(size_t)s3 * 64 + lane]);
        acc += (v0 + v1) + (v2 + v3);
    }
    for (; j < end; ++j) acc += bf2f(z[(size_t)esrc[j] * 64 + lane]);
    const float d = (float)(end - beg);
    agg[(size_t)w * 64 + lane] = f2bf(acc / fmaxf(d, 1.0f));
}

__global__ void segmax_k(const US* __restrict__ z, const int* __restrict__ batch,
                         UI* __restrict__ enc, int n, int per)
{
    const int w = blockIdx.x * 4 + (threadIdx.x >> 6);
    const int lane = threadIdx.x & 63;
    const int start = w * per;
    if (start >= n) return;
    const int end = (start + per < n) ? start + per : n;
    int g = batch[start];
    float m = -3.0e38f;
    for (int i = start; i < end; ++i) {
        const int b = batch[i];
        if (b != g) { atomicMax(&enc[(size_t)g * 64 + lane], encf(m)); g = b; m = -3.0e38f; }
        m = fmaxf(m, bf2f(z[(size_t)i * 64 + lane]));
    }
    atomicMax(&enc[(size_t)g * 64 + lane], encf(m));
}

__global__ void decode_ge(const UI* __restrict__ enc, US* __restrict__ geb)
{
    const int i = blockIdx.x * 256 + threadIdx.x;
    if (i < 4096) geb[i] = f2bf(decf(enc[i]));
}

__global__ void copy_bf2f(const US* __restrict__ z, float* __restrict__ o, long n)
{
    long i = (long)blockIdx.x * blockDim.x + threadIdx.x;
    const long stride = (long)gridDim.x * blockDim.x;
    for (; i < n; i += stride) o[i] = bf2f(z[i]);
}

// ---------------------------------------------------------------------------
extern "C" void kernel_launch(void* const* d_in, const int* in_sizes, int n_in,
                              void* d_out, int out_size, void* d_ws, size_t ws_size,
                              hipStream_t stream)
{
    (void)in_sizes; (void)n_in; (void)out_size; (void)ws_size;

    const float* x      = (const float*)d_in[0];
    const int*   batch  = (const int*)d_in[1];
    const int*   eidx   = (const int*)d_in[2];
    const int*   srcq   = (const int*)d_in[3];
    const int*   dstq   = (const int*)d_in[4];
    const float* em_in_b   = (const float*)d_in[6];
    const float* em_hid_b  = (const float*)d_in[8];
    const float* em_out_b  = (const float*)d_in[10];
    const float* em_proj_b = (const float*)d_in[12];
    const float* rho_in_b  = (const float*)d_in[14];
    const float* rho_hid_b = (const float*)d_in[16];
    const float* rho_out_b = (const float*)d_in[18];
    const float* rho_proj_b= (const float*)d_in[20];
    const float* c_ll_W[3] = {(const float*)d_in[21], (const float*)d_in[24], (const float*)d_in[27]};
    const float* c_ll_b[3] = {(const float*)d_in[22], (const float*)d_in[25], (const float*)d_in[28]};
    const float* c_lr_W[3] = {(const float*)d_in[23], (const float*)d_in[26], (const float*)d_in[29]};
    const float* h1_in_b   = (const float*)d_in[31];
    const float* h1_hid_b  = (const float*)d_in[33];
    const float* h1_out_b  = (const float*)d_in[35];
    const float* h1_proj_b = (const float*)d_in[37];
    const float* h2_in_b   = (const float*)d_in[39];
    const float* h2_hid_b  = (const float*)d_in[41];
    const float* h2_out_W  = (const float*)d_in[42];
    const float* h2_out_b  = (const float*)d_in[43];

    const int N = 50000, E = 1600000, Q = 500000;
    float* out = (float*)d_out;

    // ---- workspace layout ----
    char* wsb = (char*)d_ws;
    size_t off = 0;
    auto ALLOC = [&](size_t bytes) -> char* {
        char* p = wsb + off; off = (off + bytes + 255) & ~(size_t)255; return p;
    };
    US*  WB   = (US*)ALLOC((size_t)W_TOTAL * 2);
    US*  Ss   = (US*)ALLOC((size_t)N * 512 * 2);
    US*  z0   = (US*)ALLOC((size_t)N * 64 * 2);
    US*  z1   = (US*)ALLOC((size_t)N * 64 * 2);
    US*  aggB = (US*)ALLOC((size_t)N * 64 * 2);
    int* cnt  = (int*)ALLOC((size_t)N * 4);
    int* indp = (int*)ALLOC((size_t)(N + 1) * 4);
    int* curs = (int*)ALLOC((size_t)N * 4);
    int* esrc = (int*)ALLOC((size_t)E * 4);
    UI*  enc  = (UI*)ALLOC(4096 * 4);
    US*  geb  = (US*)ALLOC(4096 * 2);

    const int catOff[3] = {O_Cat1, O_Cat2, O_Cat3};

    WPrm pw; int si = 0;
    auto SEG = [&](const float* s, int o, int n, int rl, int ldd) {
        pw.s[si].src = s; pw.s[si].dst = o; pw.s[si].n = n; pw.s[si].rl = rl; pw.s[si].ldd = ldd; ++si;
    };
    SEG((const float*)d_in[5],  O_EmW1,          65536, 65536, 65536);
    SEG((const float*)d_in[11], O_EmW1 + 65536,  65536, 65536, 65536);
    SEG((const float*)d_in[7],  O_EmWh,          16384, 16384, 16384);
    SEG((const float*)d_in[9],  O_EmWo,          65536, 65536, 65536);
    SEG((const float*)d_in[13], O_RhoW1,         65536, 65536, 65536);
    SEG((const float*)d_in[19], O_RhoW1 + 65536, 65536, 65536, 65536);
    SEG((const float*)d_in[15], O_RhoWh,         16384, 16384, 16384);
    SEG((const float*)d_in[17], O_RhoWo,          8192,  8192,  8192);
    for (int i = 0; i < 3; ++i) {
        SEG(c_ll_W[i], catOff[i],      4096, 64, 128);
        SEG(c_lr_W[i], catOff[i] + 64, 4096, 64, 128);
    }
    SEG((const float*)d_in[30], O_H1W1,          24576, 24576, 24576);
    SEG((const float*)d_in[36], O_H1W1 + 24576,  24576, 24576, 24576);
    SEG((const float*)d_in[32], O_H1Wh,          16384, 16384, 16384);
    SEG((const float*)d_in[34], O_H1Wo,          16384, 16384, 16384);
    SEG((const float*)d_in[38], O_H2W1,          16384, 16384, 16384);
    SEG((const float*)d_in[40], O_H2Wh,          16384, 16384, 16384);
    prep_w<<<dim3(20), dim3(256), 0, stream>>>(pw, WB);

    // ---- CSR build ----
    hipMemsetAsync(cnt, 0, (size_t)N * 4, stream);
    count_k<<<dim3((E + 255) / 256), dim3(256), 0, stream>>>(eidx + E, cnt, E);
    scan_csr<<<dim3(1), dim3(1024), 0, stream>>>(cnt, N, indp, curs);
    fill_k<<<dim3((E + 255) / 256), dim3(256), 0, stream>>>(eidx, eidx + E, curs, esrc, E);

    // ---- Embedder + rho ----
    embed_fused<<<dim3(3125), dim3(1024), 0, stream>>>(x, WB, em_in_b, em_proj_b, em_hid_b, em_out_b, Ss);
    rho_fused<<<dim3((N + 63) / 64), dim3(512), 0, stream>>>(Ss, WB, rho_in_b, rho_proj_b, rho_hid_b, rho_out_b, z0, N);

    // ---- 3x SAGE residual ----
    US* zin = z0; US* zout = z1;
    for (int ci = 0; ci < 3; ++ci) {
        sage_agg<<<dim3((N + 3) / 4), dim3(256), 0, stream>>>(zin, indp, esrc, aggB, N);
        sage_gemm<<<dim3((N + 127) / 128), dim3(256), 0, stream>>>(zin, aggB, WB + catOff[ci], c_ll_b[ci], zout, N);
        US* t = zin; zin = zout; zout = t;
    }
    US* zf = zin;

    // ---- graph max-pool ----
    hipMemsetAsync(enc, 0, 4096 * 4, stream);
    segmax_k<<<dim3((N + 511) / 512), dim3(256), 0, stream>>>(zf, batch, enc, N, 128);
    decode_ge<<<dim3(16), dim3(256), 0, stream>>>(enc, geb);

    // ---- node_embeddings output ----
    copy_bf2f<<<dim3(2048), dim3(256), 0, stream>>>(zf, out, (long)N * 64);

    // ---- fused heads (64 queries/block, both sides, 16 waves/block) ----
    head_fused<<<dim3((Q + 63) / 64), dim3(1024), 0, stream>>>(
        srcq, dstq, batch, zf, geb, WB,
        h1_in_b, h1_proj_b, h1_hid_b, h1_out_b, h2_in_b, h2_hid_b, h2_out_W, h2_out_b,
        out + (size_t)N * 64, out + (size_t)N * 64 + 2 * (size_t)Q, Q);
}

// Round 10
// 1815.975 us; speedup vs baseline: 1.1975x; 1.1037x over previous
//
#include <hip/hip_runtime.h>

typedef unsigned short US;
typedef unsigned int   UI;
typedef short  short8 __attribute__((ext_vector_type(8)));
typedef US     u16x8  __attribute__((ext_vector_type(8)));
typedef float  f32x4  __attribute__((ext_vector_type(4)));

#define DEVI __device__ __forceinline__

DEVI float bf2f(US u){ UI i = ((UI)u) << 16; float f; __builtin_memcpy(&f, &i, 4); return f; }
DEVI US f2bf(float x){ UI i; __builtin_memcpy(&i, &x, 4); UI r = (i + 0x7FFFu + ((i >> 16) & 1u)) >> 16; return (US)r; }
// gelu via tanh-form written as sigmoid: x * sigmoid(1.5957691*(x + 0.044715 x^3))
// max |delta| vs exact erf-gelu ~1e-3 absolute << bf16 tolerance margin. NaN-safe.
DEVI float gelu_f(float x){
    float x2 = x * x;
    float u  = x * fmaf(x2, 0.0713548193f, 1.5957691216f);
    float e  = __expf(-u);          // u>>0 -> e=0 -> x ; u<<0 -> e=inf -> x/inf = 0
    return x / (1.0f + e);
}
DEVI UI encf(float f){ UI u; __builtin_memcpy(&u, &f, 4); return (u & 0x80000000u) ? ~u : (u | 0x80000000u); }
DEVI float decf(UI u){ UI b = (u & 0x80000000u) ? (u ^ 0x80000000u) : ~u; float f; __builtin_memcpy(&f, &b, 4); return f; }
DEVI int swz(int r, int c, int ld){ int i = r * ld + c; return i ^ ((r & 7) << 3); }

// packed f32x2 -> bf16x2 (hardware RNE), T12 recipe: no builtin on gfx950
DEVI UI pkbf(float a, float b){ UI u; asm("v_cvt_pk_bf16_f32 %0, %1, %2" : "=v"(u) : "v"(a), "v"(b)); return u; }
// store 4 consecutive bf16 (col % 4 == 0) with one 8B write
DEVI void st4(US* T, int row, int col, float v0, float v1, float v2, float v3){
    uint2 p; p.x = pkbf(v0, v1); p.y = pkbf(v2, v3);
    *(uint2*)&T[swz(row, col, 256)] = p;
}
// load 4 consecutive bf16 as f32
DEVI void ld4(const US* T, int row, int col, float& v0, float& v1, float& v2, float& v3){
    uint2 q = *(const uint2*)&T[swz(row, col, 256)];
    v0 = bf2f((US)(q.x & 0xffff)); v1 = bf2f((US)(q.x >> 16));
    v2 = bf2f((US)(q.y & 0xffff)); v3 = bf2f((US)(q.y >> 16));
}

// bf16 weight-buffer offsets (elements)
enum : int { O_EmW1 = 0, O_EmWh = 131072, O_EmWo = 147456, O_RhoW1 = 212992,
             O_RhoWh = 344064, O_RhoWo = 360448, O_Cat1 = 368640, O_Cat2 = 376832,
             O_Cat3 = 385024, O_H1W1 = 393216, O_H1Wh = 442368, O_H1Wo = 458752,
             O_H2W1 = 475136, O_H2Wh = 491520, W_TOTAL = 507904 };

// ---------------------------------------------------------------------------
// Double-buffered W-streaming stage. SWAP=false: C[xrow, wcol] (R9 behavior,
// acc r-index = rows). SWAP=true: operands swapped -> C^T: acc r-index = 4
// CONSECUTIVE feature-cols of one query row (lane&15) -> packed epilogues.
// Read patterns identical in both modes (A/B fragment layouts symmetric).
// ONE barrier per kc. Trailing barrier protects Wb + T1 WAR.
// ---------------------------------------------------------------------------
template<int NT, int NKC, int NTHR, bool SWAP = false>
DEVI void stageWD(const US* __restrict__ Wg, int Kw, const US* __restrict__ A, int lda,
                  int ab0, int ab1, int ab2, int arow0, US* Wb, int tid, f32x4 (&acc)[NT])
{
    const int lane = tid & 63;
    const int wc = (tid >> 6) & 1;
    constexpr int SLAB = NT * 32 * 64;
    #pragma unroll
    for (int n = 0; n < NT; ++n) acc[n] = (f32x4){0.f, 0.f, 0.f, 0.f};
    constexpr int J = (NT * 256) / NTHR;
    u16x8 wreg[J];
    #pragma unroll
    for (int j = 0; j < J; ++j) {
        const int c = tid + NTHR * j;
        wreg[j] = *(const u16x8*)(Wg + (size_t)(c >> 3) * Kw + (c & 7) * 8);
    }
    #pragma unroll
    for (int j = 0; j < J; ++j) {
        const int c = tid + NTHR * j;
        *(u16x8*)&Wb[swz(c >> 3, (c & 7) * 8, 64)] = wreg[j];
    }
    #pragma unroll
    for (int kc = 0; kc < NKC; ++kc) {
        __syncthreads();            // slab kc&1 + prior-stage T1 visible
        if (kc + 1 < NKC) {
            #pragma unroll
            for (int j = 0; j < J; ++j) {
                const int c = tid + NTHR * j;
                wreg[j] = *(const u16x8*)(Wg + (size_t)(c >> 3) * Kw + (kc + 1) * 64 + (c & 7) * 8);
            }
        }
        const int ab = (kc == 0) ? ab0 : ((kc == 1) ? ab1 : ab2);
        const int bufr = (kc & 1) * SLAB;
        #pragma unroll
        for (int sub = 0; sub < 2; ++sub) {
            const int kk = sub * 32 + ((lane >> 4) << 3);
            short8 a = *(const short8*)&A[swz(arow0 + (lane & 15), ab + kk, lda)];
            #pragma unroll
            for (int n = 0; n < NT; ++n) {
                short8 b = *(const short8*)&Wb[bufr + swz(wc * (NT * 16) + n * 16 + (lane & 15), kk, 64)];
                if (SWAP) acc[n] = __builtin_amdgcn_mfma_f32_16x16x32_bf16(b, a, acc[n], 0, 0, 0);
                else      acc[n] = __builtin_amdgcn_mfma_f32_16x16x32_bf16(a, b, acc[n], 0, 0, 0);
            }
        }
        if (kc + 1 < NKC) {
            const int bufw = ((kc + 1) & 1) * SLAB;
            #pragma unroll
            for (int j = 0; j < J; ++j) {
                const int c = tid + NTHR * j;
                *(u16x8*)&Wb[bufw + swz(c >> 3, (c & 7) * 8, 64)] = wreg[j];
            }
        }
    }
    __syncthreads();                // all Wb/T1 reads done before reuse
}

// ---------------------------------------------------------------------------
// Fused embedder: 128 point-rows (16 nodes) per block, 1024 threads (16 waves).
// (unchanged from R9, cheaper gelu)
// ---------------------------------------------------------------------------
__global__ __launch_bounds__(1024, 4)
void embed_fused(const float* __restrict__ x, const US* __restrict__ WB,
                 const float* __restrict__ b_in, const float* __restrict__ b_proj,
                 const float* __restrict__ b_hid, const float* __restrict__ b_out,
                 US* __restrict__ Ss)
{
    __shared__ __align__(16) US T1[128 * 256];
    __shared__ __align__(16) US Wb[2 * 16384];
    __shared__ __align__(16) US As[128 * 64];
    const int tid = threadIdx.x, lane = tid & 63, w = tid >> 6;
    const int wr = w >> 1, wc = w & 1;
    const int grow0 = blockIdx.x * 128;
    const int row0 = wr * 16 + ((lane >> 4) << 2);

    { // ---- stage 1: out 256, K=512 (8 kc) ----
        f32x4 acc[8];
        #pragma unroll
        for (int n = 0; n < 8; ++n) acc[n] = (f32x4){0.f, 0.f, 0.f, 0.f};
        const float* xr = x + (size_t)(grow0 + (tid >> 3)) * 512 + (tid & 7) * 8;
        float4 a0, a1;
        u16x8 wreg[2];
        auto loadA = [&](int kc) { a0 = *(const float4*)(xr + kc * 64); a1 = *(const float4*)(xr + kc * 64 + 4); };
        auto loadW = [&](int kc) {
            #pragma unroll
            for (int j = 0; j < 2; ++j) {
                const int c = tid + 1024 * j;
                wreg[j] = *(const u16x8*)(WB + O_EmW1 + (size_t)(c >> 3) * 512 + kc * 64 + (c & 7) * 8);
            }
        };
        loadA(0); loadW(0);
        for (int kc = 0; kc < 8; ++kc) {
            __syncthreads();
            {
                u16x8 v;
                v[0] = f2bf(a0.x); v[1] = f2bf(a0.y); v[2] = f2bf(a0.z); v[3] = f2bf(a0.w);
                v[4] = f2bf(a1.x); v[5] = f2bf(a1.y); v[6] = f2bf(a1.z); v[7] = f2bf(a1.w);
                *(u16x8*)&As[swz(tid >> 3, (tid & 7) * 8, 64)] = v;
                #pragma unroll
                for (int j = 0; j < 2; ++j) {
                    const int c = tid + 1024 * j;
                    *(u16x8*)&Wb[swz(c >> 3, (c & 7) * 8, 64)] = wreg[j];
                }
            }
            __syncthreads();
            if (kc < 7) { loadA(kc + 1); loadW(kc + 1); }
            #pragma unroll
            for (int sub = 0; sub < 2; ++sub) {
                const int kk = sub * 32 + ((lane >> 4) << 3);
                short8 a = *(const short8*)&As[swz(wr * 16 + (lane & 15), kk, 64)];
                #pragma unroll
                for (int n = 0; n < 8; ++n) {
                    short8 b = *(const short8*)&Wb[swz(wc * 128 + n * 16 + (lane & 15), kk, 64)];
                    acc[n] = __builtin_amdgcn_mfma_f32_16x16x32_bf16(a, b, acc[n], 0, 0, 0);
                }
            }
        }
        __syncthreads();
        #pragma unroll
        for (int n = 0; n < 8; ++n) {
            const int col = wc * 128 + n * 16 + (lane & 15);
            const float bv = (col < 128) ? b_in[col] : b_proj[col - 128];
            #pragma unroll
            for (int r = 0; r < 4; ++r) {
                float v = acc[n][r] + bv;
                if (col < 128) v = gelu_f(v);
                T1[swz(row0 + r, col, 256)] = f2bf(v);
            }
        }
    }
    { // ---- stage 2: U = s + gelu(t1@Wh+bh) -> T1 lo ----
        f32x4 acc[4];
        stageWD<4, 2, 1024>(WB + O_EmWh, 128, T1, 256, 0, 64, 0, wr * 16, Wb, tid, acc);
        #pragma unroll
        for (int n = 0; n < 4; ++n) {
            const int col = wc * 64 + n * 16 + (lane & 15);
            const float bv = b_hid[col];
            #pragma unroll
            for (int r = 0; r < 4; ++r) {
                const float sv = bf2f(T1[swz(row0 + r, 128 + col, 256)]);
                T1[swz(row0 + r, col, 256)] = f2bf(gelu_f(acc[n][r] + bv) + sv);
            }
        }
    }
    // ---- stage 3: 2 merged passes (NT=8, 256 cols each), sum8 epilogue ----
    for (int p2 = 0; p2 < 2; ++p2) {
        f32x4 acc[8];
        stageWD<8, 2, 1024>(WB + O_EmWo + (size_t)(p2 * 256) * 128, 128, T1, 256, 0, 64, 0, wr * 16, Wb, tid, acc);
        #pragma unroll
        for (int n = 0; n < 8; ++n) {
            const int col = wc * 128 + n * 16 + (lane & 15);
            const float bv = b_out[p2 * 256 + col];
            float s = 0.f;
            #pragma unroll
            for (int r = 0; r < 4; ++r) s += gelu_f(acc[n][r] + bv);
            s += __shfl_xor(s, 16);
            if (((lane >> 4) & 1) == 0) {
                const int node = (grow0 >> 3) + wr * 2 + (lane >> 5);
                Ss[(size_t)node * 512 + p2 * 256 + col] = f2bf(s);
            }
        }
    }
}

// ---------------------------------------------------------------------------
// Fused rho: 64 nodes per block, 512 threads (unchanged from R9).
// ---------------------------------------------------------------------------
__global__ __launch_bounds__(512, 2)
void rho_fused(const US* __restrict__ Ss, const US* __restrict__ WB,
               const float* __restrict__ b_in, const float* __restrict__ b_proj,
               const float* __restrict__ b_hid, const float* __restrict__ b_out,
               US* __restrict__ zo, int N)
{
    __shared__ __align__(16) US T1[64 * 256];
    __shared__ __align__(16) US Wb[256 * 64];
    __shared__ __align__(16) US As[64 * 64];
    const int tid = threadIdx.x, lane = tid & 63, w = tid >> 6;
    const int wr = w >> 1, wc = w & 1;
    const int grow0 = blockIdx.x * 64;
    const int row0 = wr * 16 + ((lane >> 4) << 2);

    { // ---- stage 1: out 256, K=512 ----
        f32x4 acc[8];
        #pragma unroll
        for (int n = 0; n < 8; ++n) acc[n] = (f32x4){0.f, 0.f, 0.f, 0.f};
        int arow = grow0 + (tid >> 3); if (arow >= N) arow = N - 1;
        const US* srow = Ss + (size_t)arow * 512 + (tid & 7) * 8;
        u16x8 areg, wreg[4];
        auto loadA = [&](int kc) { areg = *(const u16x8*)(srow + kc * 64); };
        auto loadW = [&](int kc) {
            #pragma unroll
            for (int j = 0; j < 4; ++j) {
                const int c = tid + 512 * j;
                wreg[j] = *(const u16x8*)(WB + O_RhoW1 + (size_t)(c >> 3) * 512 + kc * 64 + (c & 7) * 8);
            }
        };
        loadA(0); loadW(0);
        for (int kc = 0; kc < 8; ++kc) {
            __syncthreads();
            *(u16x8*)&As[swz(tid >> 3, (tid & 7) * 8, 64)] = areg;
            #pragma unroll
            for (int j = 0; j < 4; ++j) {
                const int c = tid + 512 * j;
                *(u16x8*)&Wb[swz(c >> 3, (c & 7) * 8, 64)] = wreg[j];
            }
            __syncthreads();
            if (kc < 7) { loadA(kc + 1); loadW(kc + 1); }
            #pragma unroll
            for (int sub = 0; sub < 2; ++sub) {
                const int kk = sub * 32 + ((lane >> 4) << 3);
                short8 a = *(const short8*)&As[swz(wr * 16 + (lane & 15), kk, 64)];
                #pragma unroll
                for (int n = 0; n < 8; ++n) {
                    short8 b = *(const short8*)&Wb[swz(wc * 128 + n * 16 + (lane & 15), kk, 64)];
                    acc[n] = __builtin_amdgcn_mfma_f32_16x16x32_bf16(a, b, acc[n], 0, 0, 0);
                }
            }
        }
        __syncthreads();
        #pragma unroll
        for (int n = 0; n < 8; ++n) {
            const int col = wc * 128 + n * 16 + (lane & 15);
            const float bv = (col < 128) ? b_in[col] : b_proj[col - 128];
            #pragma unroll
            for (int r = 0; r < 4; ++r) {
                float v = acc[n][r] + bv;
                if (col < 128) v = gelu_f(v);
                T1[swz(row0 + r, col, 256)] = f2bf(v);
            }
        }
    }
    { // ---- stage 2: RU -> T1 lo ----
        f32x4 acc[4];
        stageWD<4, 2, 512>(WB + O_RhoWh, 128, T1, 256, 0, 64, 0, wr * 16, Wb, tid, acc);
        #pragma unroll
        for (int n = 0; n < 4; ++n) {
            const int col = wc * 64 + n * 16 + (lane & 15);
            const float bv = b_hid[col];
            #pragma unroll
            for (int r = 0; r < 4; ++r) {
                const float sv = bf2f(T1[swz(row0 + r, 128 + col, 256)]);
                T1[swz(row0 + r, col, 256)] = f2bf(gelu_f(acc[n][r] + bv) + sv);
            }
        }
    }
    { // ---- stage 3: out 64 ----
        f32x4 acc[2];
        stageWD<2, 2, 512>(WB + O_RhoWo, 128, T1, 256, 0, 64, 0, wr * 16, Wb, tid, acc);
        #pragma unroll
        for (int n = 0; n < 2; ++n) {
            const int col = wc * 32 + n * 16 + (lane & 15);
            const float bv = b_out[col];
            #pragma unroll
            for (int r = 0; r < 4; ++r) {
                const int node = grow0 + row0 + r;
                if (node < N) zo[(size_t)node * 64 + col] = f2bf(acc[n][r] + bv);
            }
        }
    }
}

// ---------------------------------------------------------------------------
// Fused head v6: R9 geometry + SWAP'd MFMA (packed epilogues) + merged S1.
// 64 queries/block, 1024 threads (16 waves), both sides share every W pass.
// T1 rows 0-63 = xy, 64-127 = yx. Wave: wr=w>>1 rows, wc=w&1 feature half.
// SWAP epilogue: thread holds 4 consecutive feature-cols of row lane&15.
// LDS: A0 24KB + T1 64KB + Wb 64KB + wout 0.5KB = 152.5KB -> 1 block, 16 waves.
// ---------------------------------------------------------------------------
__global__ __launch_bounds__(1024, 4)
void head_fused(const int* __restrict__ srcq, const int* __restrict__ dstq,
                const int* __restrict__ batch, const US* __restrict__ z,
                const US* __restrict__ geb, const US* __restrict__ WB,
                const float* __restrict__ b1_in, const float* __restrict__ b1_proj,
                const float* __restrict__ b1_hid, const float* __restrict__ b1_out,
                const float* __restrict__ b2_in, const float* __restrict__ b2_hid,
                const float* __restrict__ w2_out, const float* __restrict__ b2_out,
                float* __restrict__ outH, float* __restrict__ outXY, int Q)
{
    __shared__ __align__(16) US A0[64 * 192];
    __shared__ __align__(16) US T1[128 * 256];
    __shared__ __align__(16) US Wb[2 * 16384];
    __shared__ float wout_s[128];
    const int tid = threadIdx.x, lane = tid & 63, w = tid >> 6;
    const int wr = w >> 1, wc = w & 1;
    const int q0 = blockIdx.x * 64;
    // side-dependent S1 K-chunk order: side0 {0,64,128}, side1 {64,0,128}
    const int s1a = (wr < 4) ? 0 : 64;
    const int s1b = (wr < 4) ? 64 : 0;
    const int arowS1 = (wr & 3) * 16;
    const int rowS1 = (wr >> 2) * 64 + arowS1 + (lane & 15);   // T1 row (S1)
    const int rowT  = wr * 16 + (lane & 15);                   // T1 row (S2-S5)
    { // gather: 8 threads per query row (512 threads active)
        if (tid < 512) {
            const int r = tid >> 3, h = tid & 7;
            const int q = q0 + r;
            const int qc = (q < Q) ? q : (Q - 1);
            const int s = srcq[qc], d = dstq[qc];
            const int g = batch[s];
            *(u16x8*)&A0[swz(r, h * 8, 192)]       = *(const u16x8*)(z + (size_t)s * 64 + h * 8);
            *(u16x8*)&A0[swz(r, 64 + h * 8, 192)]  = *(const u16x8*)(z + (size_t)d * 64 + h * 8);
            *(u16x8*)&A0[swz(r, 128 + h * 8, 192)] = *(const u16x8*)(geb + (size_t)g * 64 + h * 8);
        }
        if (tid < 128) wout_s[tid] = w2_out[tid];
    }
    __syncthreads();
    { // xy output (f32): 64 rows x 48 float4 = 3072
        #pragma unroll
        for (int jj = 0; jj < 3; ++jj) {
            const int f = tid + 1024 * jj;
            const int row = f / 48;
            const int c4 = (f - row * 48) * 4;
            if (q0 + row < Q) {
                const US* p = &A0[swz(row, c4, 192)];
                float4 o;
                o.x = bf2f(p[0]); o.y = bf2f(p[1]); o.z = bf2f(p[2]); o.w = bf2f(p[3]);
                *(float4*)&outXY[(size_t)(q0 + row) * 192 + c4] = o;
            }
        }
    }
    { // S1 merged: [t1 | s1] = A0 @ [W1in ; Wproj]^T, out 256 cols, K=192
        f32x4 acc8[8];
        stageWD<8, 3, 1024, true>(WB + O_H1W1, 192, A0, 192, s1a, s1b, 128, arowS1, Wb, tid, acc8);
        #pragma unroll
        for (int n = 0; n < 8; ++n) {
            const int col = wc * 128 + n * 16 + ((lane >> 4) << 2);
            float4 bv = (col < 128) ? *(const float4*)&b1_in[col]
                                    : *(const float4*)&b1_proj[col - 128];
            float v0 = acc8[n][0] + bv.x, v1 = acc8[n][1] + bv.y;
            float v2 = acc8[n][2] + bv.z, v3 = acc8[n][3] + bv.w;
            if (col < 128) { v0 = gelu_f(v0); v1 = gelu_f(v1); v2 = gelu_f(v2); v3 = gelu_f(v3); }
            st4(T1, rowS1, col, v0, v1, v2, v3);
        }
    }
    f32x4 acc[4];
    // S2: U = s1 + gelu(t1@Wh + bh) -> T1 lo
    stageWD<4, 2, 1024, true>(WB + O_H1Wh, 128, T1, 256, 0, 64, 0, wr * 16, Wb, tid, acc);
    #pragma unroll
    for (int n = 0; n < 4; ++n) {
        const int col = wc * 64 + n * 16 + ((lane >> 4) << 2);
        float4 bv = *(const float4*)&b1_hid[col];
        float s0, s1, s2, s3;
        ld4(T1, rowT, 128 + col, s0, s1, s2, s3);
        st4(T1, rowT, col,
            gelu_f(acc[0 + n][0] * 0.f + acc[n][0] + bv.x) + s0,   // (kept explicit below)
            gelu_f(acc[n][1] + bv.y) + s1,
            gelu_f(acc[n][2] + bv.z) + s2,
            gelu_f(acc[n][3] + bv.w) + s3);
    }
    // S3: T = relu(U@Wo + bo) -> T1 hi
    stageWD<4, 2, 1024, true>(WB + O_H1Wo, 128, T1, 256, 0, 64, 0, wr * 16, Wb, tid, acc);
    #pragma unroll
    for (int n = 0; n < 4; ++n) {
        const int col = wc * 64 + n * 16 + ((lane >> 4) << 2);
        float4 bv = *(const float4*)&b1_out[col];
        st4(T1, rowT, 128 + col,
            fmaxf(acc[n][0] + bv.x, 0.f), fmaxf(acc[n][1] + bv.y, 0.f),
            fmaxf(acc[n][2] + bv.z, 0.f), fmaxf(acc[n][3] + bv.w, 0.f));
    }
    // S4: B1 = gelu(T@W2 + b2) -> T1 lo (A = T1 hi)
    stageWD<4, 2, 1024, true>(WB + O_H2W1, 128, T1, 256, 128, 192, 0, wr * 16, Wb, tid, acc);
    #pragma unroll
    for (int n = 0; n < 4; ++n) {
        const int col = wc * 64 + n * 16 + ((lane >> 4) << 2);
        float4 bv = *(const float4*)&b2_in[col];
        st4(T1, rowT, col,
            gelu_f(acc[n][0] + bv.x), gelu_f(acc[n][1] + bv.y),
            gelu_f(acc[n][2] + bv.z), gelu_f(acc[n][3] + bv.w));
    }
    // S5: U2 = T + gelu(B1@Wh2 + bh2) -> T1 lo
    stageWD<4, 2, 1024, true>(WB + O_H2Wh, 128, T1, 256, 0, 64, 0, wr * 16, Wb, tid, acc);
    #pragma unroll
    for (int n = 0; n < 4; ++n) {
        const int col = wc * 64 + n * 16 + ((lane >> 4) << 2);
        float4 bv = *(const float4*)&b2_hid[col];
        float t0, t1, t2, t3;
        ld4(T1, rowT, 128 + col, t0, t1, t2, t3);
        st4(T1, rowT, col,
            gelu_f(acc[n][0] + bv.x) + t0, gelu_f(acc[n][1] + bv.y) + t1,
            gelu_f(acc[n][2] + bv.z) + t2, gelu_f(acc[n][3] + bv.w) + t3);
    }
    __syncthreads();   // U2 visible before dot (cross-wave rows)
    // S6: scalar head: 128 rows x 8 threads, 16 cols each
    {
        const int r = tid >> 3, h = tid & 7;   // r 0..127: side = r>>6
        float a = 0.f;
        u16x8 v0 = *(const u16x8*)&T1[swz(r, h * 16, 256)];
        u16x8 v1 = *(const u16x8*)&T1[swz(r, h * 16 + 8, 256)];
        #pragma unroll
        for (int e = 0; e < 8; ++e) {
            a += bf2f(v0[e]) * wout_s[h * 16 + e];
            a += bf2f(v1[e]) * wout_s[h * 16 + 8 + e];
        }
        a += __shfl_xor(a, 4);
        a += __shfl_xor(a, 2);
        a += __shfl_xor(a, 1);
        const int q = q0 + (r & 63);
        if ((lane & 7) == 0 && q < Q) outH[(size_t)(r >> 6) * Q + q] = a + b2_out[0];
    }
}

// ---------------------------------------------------------------------------
// SAGE layer: zout = zin + gelu( [agg|zin] @ Wcat^T + bl ), K=128, out 64
// ---------------------------------------------------------------------------
__global__ __launch_bounds__(256, 2)
void sage_gemm(const US* __restrict__ zin, const US* __restrict__ agg,
               const US* __restrict__ Wc, const float* __restrict__ bias,
               US* __restrict__ zout, int N)
{
    __shared__ __align__(16) US As[128 * 128];
    __shared__ __align__(16) US Ws[64 * 128];
    const int tid = threadIdx.x, lane = tid & 63, w = tid >> 6;
    const int grow0 = blockIdx.x * 128;
    {
        const int r = tid >> 1, h = tid & 1;
        int row = grow0 + r; if (row >= N) row = N - 1;
        const US* src = h ? (zin + (size_t)row * 64) : (agg + (size_t)row * 64);
        #pragma unroll
        for (int j = 0; j < 8; ++j)
            *(u16x8*)&As[swz(r, h * 64 + 8 * j, 128)] = *(const u16x8*)(src + 8 * j);
    }
    #pragma unroll
    for (int j = 0; j < 4; ++j) {
        const int c = tid + 256 * j;
        *(u16x8*)&Ws[swz(c >> 4, (c & 15) * 8, 128)] =
            *(const u16x8*)(Wc + (size_t)(c >> 4) * 128 + (c & 15) * 8);
    }
    __syncthreads();
    const int rbw = w * 32;
    f32x4 acc[2][4];
    #pragma unroll
    for (int m = 0; m < 2; ++m)
        #pragma unroll
        for (int n = 0; n < 4; ++n) acc[m][n] = (f32x4){0.f, 0.f, 0.f, 0.f};
    #pragma unroll
    for (int kc = 0; kc < 2; ++kc)
        #pragma unroll
        for (int sub = 0; sub < 2; ++sub) {
            const int kk = kc * 64 + sub * 32 + ((lane >> 4) << 3);
            short8 a[2], b[4];
            #pragma unroll
            for (int m = 0; m < 2; ++m) a[m] = *(const short8*)&As[swz(rbw + m * 16 + (lane & 15), kk, 128)];
            #pragma unroll
            for (int n = 0; n < 4; ++n) b[n] = *(const short8*)&Ws[swz(n * 16 + (lane & 15), kk, 128)];
            #pragma unroll
            for (int m = 0; m < 2; ++m)
                #pragma unroll
                for (int n = 0; n < 4; ++n)
                    acc[m][n] = __builtin_amdgcn_mfma_f32_16x16x32_bf16(a[m], b[n], acc[m][n], 0, 0, 0);
        }
    #pragma unroll
    for (int m = 0; m < 2; ++m) {
        const int row0 = rbw + m * 16 + ((lane >> 4) << 2);
        #pragma unroll
        for (int n = 0; n < 4; ++n) {
            const int col = n * 16 + (lane & 15);
            const float bv = bias[col];
            #pragma unroll
            for (int r = 0; r < 4; ++r) {
                const int node = grow0 + row0 + r;
                if (node < N) {
                    const float v = gelu_f(acc[m][n][r] + bv) + bf2f(zin[(size_t)node * 64 + col]);
                    zout[(size_t)node * 64 + col] = f2bf(v);
                }
            }
        }
    }
}

// ---------------------------------------------------------------------------
// Weight prep (f32 -> bf16, strided stacking)
// ---------------------------------------------------------------------------
struct WSeg { const float* src; int dst; int n; int rl; int ldd; };
struct WPrm { WSeg s[20]; };

__global__ void prep_w(WPrm p, US* __restrict__ wb)
{
    WSeg sg = p.s[blockIdx.x];
    for (int i = threadIdx.x; i < sg.n; i += 256) {
        const int idx = sg.dst + (i / sg.rl) * sg.ldd + (i % sg.rl);
        wb[idx] = f2bf(sg.src[i]);
    }
}

// ---------------------------------------------------------------------------
// CSR build + aggregate + segment max + misc
// ---------------------------------------------------------------------------
__global__ void count_k(const int* __restrict__ dst, int* __restrict__ cnt, int E)
{
    int e = blockIdx.x * 256 + threadIdx.x;
    if (e < E) atomicAdd(&cnt[dst[e]], 1);
}

__global__ void scan_csr(const int* __restrict__ cnt, int n, int* __restrict__ indp, int* __restrict__ curs)
{
    __shared__ int wsum[16];
    __shared__ int carry_s;
    const int tid = threadIdx.x, lane = tid & 63, w = tid >> 6;
    if (tid == 0) carry_s = 0;
    __syncthreads();
    for (int base = 0; base < n; base += 1024) {
        const int i = base + tid;
        const int v = (i < n) ? cnt[i] : 0;
        int s = v;
        #pragma unroll
        for (int o = 1; o < 64; o <<= 1) { int t = __shfl_up(s, o); if (lane >= o) s += t; }
        if (lane == 63) wsum[w] = s;
        __syncthreads();
        if (w == 0 && lane < 16) {
            int ws2 = wsum[lane];
            #pragma unroll
            for (int o = 1; o < 16; o <<= 1) { int t = __shfl_up(ws2, o); if (lane >= o) ws2 += t; }
            wsum[lane] = ws2;
        }
        __syncthreads();
        const int carry = carry_s;
        const int woff  = (w == 0) ? 0 : wsum[w - 1];
        if (i < n) { const int excl = carry + woff + s - v; indp[i] = excl; curs[i] = excl; }
        __syncthreads();
        if (tid == 0) carry_s = carry + wsum[15];
        __syncthreads();
    }
    if (threadIdx.x == 0) indp[n] = carry_s;
}

__global__ void fill_k(const int* __restrict__ src, const int* __restrict__ dst,
                       int* __restrict__ curs, int* __restrict__ esrc, int E)
{
    int e = blockIdx.x * 256 + threadIdx.x;
    if (e < E) { int p = atomicAdd(&curs[dst[e]], 1); esrc[p] = src[e]; }
}

__global__ void sage_agg(const US* __restrict__ z, const int* __restrict__ indp,
                         const int* __restrict__ esrc, US* __restrict__ agg, int n)
{
    const int w = blockIdx.x * 4 + (threadIdx.x >> 6);
    const int lane = threadIdx.x & 63;
    if (w >= n) return;
    const int beg = indp[w], end = indp[w + 1];
    float acc = 0.f;
    int j = beg;
    for (; j + 4 <= end; j += 4) {
        const int s0 = esrc[j], s1 = esrc[j + 1], s2 = esrc[j + 2], s3 = esrc[j + 3];
        const float v0 = bf2f(z[(size_t)s0 * 64 + lane]);
        const float v1 = bf2f(z[(size_t)s1 * 64 + lane]);
        const float v2 = bf2f(z[(size_t)s2 * 64 + lane]);
        const float v3 = bf2f(z[(size_t)s3 * 64 + lane]);
        acc += (v0 + v1) + (v2 + v3);
    }
    for (; j < end; ++j) acc += bf2f(z[(size_t)esrc[j] * 64 + lane]);
    const float d = (float)(end - beg);
    agg[(size_t)w * 64 + lane] = f2bf(acc / fmaxf(d, 1.0f));
}

__global__ void segmax_k(const US* __restrict__ z, const int* __restrict__ batch,
                         UI* __restrict__ enc, int n, int per)
{
    const int w = blockIdx.x * 4 + (threadIdx.x >> 6);
    const int lane = threadIdx.x & 63;
    const int start = w * per;
    if (start >= n) return;
    const int end = (start + per < n) ? start + per : n;
    int g = batch[start];
    float m = -3.0e38f;
    for (int i = start; i < end; ++i) {
        const int b = batch[i];
        if (b != g) { atomicMax(&enc[(size_t)g * 64 + lane], encf(m)); g = b; m = -3.0e38f; }
        m = fmaxf(m, bf2f(z[(size_t)i * 64 + lane]));
    }
    atomicMax(&enc[(size_t)g * 64 + lane], encf(m));
}

__global__ void decode_ge(const UI* __restrict__ enc, US* __restrict__ geb)
{
    const int i = blockIdx.x * 256 + threadIdx.x;
    if (i < 4096) geb[i] = f2bf(decf(enc[i]));
}

__global__ void copy_bf2f(const US* __restrict__ z, float* __restrict__ o, long n)
{
    long i = (long)blockIdx.x * blockDim.x + threadIdx.x;
    const long stride = (long)gridDim.x * blockDim.x;
    for (; i < n; i += stride) o[i] = bf2f(z[i]);
}

// ---------------------------------------------------------------------------
extern "C" void kernel_launch(void* const* d_in, const int* in_sizes, int n_in,
                              void* d_out, int out_size, void* d_ws, size_t ws_size,
                              hipStream_t stream)
{
    (void)in_sizes; (void)n_in; (void)out_size; (void)ws_size;

    const float* x      = (const float*)d_in[0];
    const int*   batch  = (const int*)d_in[1];
    const int*   eidx   = (const int*)d_in[2];
    const int*   srcq   = (const int*)d_in[3];
    const int*   dstq   = (const int*)d_in[4];
    const float* em_in_b   = (const float*)d_in[6];
    const float* em_hid_b  = (const float*)d_in[8];
    const float* em_out_b  = (const float*)d_in[10];
    const float* em_proj_b = (const float*)d_in[12];
    const float* rho_in_b  = (const float*)d_in[14];
    const float* rho_hid_b = (const float*)d_in[16];
    const float* rho_out_b = (const float*)d_in[18];
    const float* rho_proj_b= (const float*)d_in[20];
    const float* c_ll_W[3] = {(const float*)d_in[21], (const float*)d_in[24], (const float*)d_in[27]};
    const float* c_ll_b[3] = {(const float*)d_in[22], (const float*)d_in[25], (const float*)d_in[28]};
    const float* c_lr_W[3] = {(const float*)d_in[23], (const float*)d_in[26], (const float*)d_in[29]};
    const float* h1_in_b   = (const float*)d_in[31];
    const float* h1_hid_b  = (const float*)d_in[33];
    const float* h1_out_b  = (const float*)d_in[35];
    const float* h1_proj_b = (const float*)d_in[37];
    const float* h2_in_b   = (const float*)d_in[39];
    const float* h2_hid_b  = (const float*)d_in[41];
    const float* h2_out_W  = (const float*)d_in[42];
    const float* h2_out_b  = (const float*)d_in[43];

    const int N = 50000, E = 1600000, Q = 500000;
    float* out = (float*)d_out;

    // ---- workspace layout ----
    char* wsb = (char*)d_ws;
    size_t off = 0;
    auto ALLOC = [&](size_t bytes) -> char* {
        char* p = wsb + off; off = (off + bytes + 255) & ~(size_t)255; return p;
    };
    US*  WB   = (US*)ALLOC((size_t)W_TOTAL * 2);
    US*  Ss   = (US*)ALLOC((size_t)N * 512 * 2);
    US*  z0   = (US*)ALLOC((size_t)N * 64 * 2);
    US*  z1   = (US*)ALLOC((size_t)N * 64 * 2);
    US*  aggB = (US*)ALLOC((size_t)N * 64 * 2);
    int* cnt  = (int*)ALLOC((size_t)N * 4);
    int* indp = (int*)ALLOC((size_t)(N + 1) * 4);
    int* curs = (int*)ALLOC((size_t)N * 4);
    int* esrc = (int*)ALLOC((size_t)E * 4);
    UI*  enc  = (UI*)ALLOC(4096 * 4);
    US*  geb  = (US*)ALLOC(4096 * 2);

    const int catOff[3] = {O_Cat1, O_Cat2, O_Cat3};

    WPrm pw; int si = 0;
    auto SEG = [&](const float* s, int o, int n, int rl, int ldd) {
        pw.s[si].src = s; pw.s[si].dst = o; pw.s[si].n = n; pw.s[si].rl = rl; pw.s[si].ldd = ldd; ++si;
    };
    SEG((const float*)d_in[5],  O_EmW1,          65536, 65536, 65536);
    SEG((const float*)d_in[11], O_EmW1 + 65536,  65536, 65536, 65536);
    SEG((const float*)d_in[7],  O_EmWh,          16384, 16384, 16384);
    SEG((const float*)d_in[9],  O_EmWo,          65536, 65536, 65536);
    SEG((const float*)d_in[13], O_RhoW1,         65536, 65536, 65536);
    SEG((const float*)d_in[19], O_RhoW1 + 65536, 65536, 65536, 65536);
    SEG((const float*)d_in[15], O_RhoWh,         16384, 16384, 16384);
    SEG((const float*)d_in[17], O_RhoWo,          8192,  8192,  8192);
    for (int i = 0; i < 3; ++i) {
        SEG(c_ll_W[i], catOff[i],      4096, 64, 128);
        SEG(c_lr_W[i], catOff[i] + 64, 4096, 64, 128);
    }
    SEG((const float*)d_in[30], O_H1W1,          24576, 24576, 24576);
    SEG((const float*)d_in[36], O_H1W1 + 24576,  24576, 24576, 24576);
    SEG((const float*)d_in[32], O_H1Wh,          16384, 16384, 16384);
    SEG((const float*)d_in[34], O_H1Wo,          16384, 16384, 16384);
    SEG((const float*)d_in[38], O_H2W1,          16384, 16384, 16384);
    SEG((const float*)d_in[40], O_H2Wh,          16384, 16384, 16384);
    prep_w<<<dim3(20), dim3(256), 0, stream>>>(pw, WB);

    // ---- CSR build ----
    hipMemsetAsync(cnt, 0, (size_t)N * 4, stream);
    count_k<<<dim3((E + 255) / 256), dim3(256), 0, stream>>>(eidx + E, cnt, E);
    scan_csr<<<dim3(1), dim3(1024), 0, stream>>>(cnt, N, indp, curs);
    fill_k<<<dim3((E + 255) / 256), dim3(256), 0, stream>>>(eidx, eidx + E, curs, esrc, E);

    // ---- Embedder + rho ----
    embed_fused<<<dim3(3125), dim3(1024), 0, stream>>>(x, WB, em_in_b, em_proj_b, em_hid_b, em_out_b, Ss);
    rho_fused<<<dim3((N + 63) / 64), dim3(512), 0, stream>>>(Ss, WB, rho_in_b, rho_proj_b, rho_hid_b, rho_out_b, z0, N);

    // ---- 3x SAGE residual ----
    US* zin = z0; US* zout = z1;
    for (int ci = 0; ci < 3; ++ci) {
        sage_agg<<<dim3((N + 3) / 4), dim3(256), 0, stream>>>(zin, indp, esrc, aggB, N);
        sage_gemm<<<dim3((N + 127) / 128), dim3(256), 0, stream>>>(zin, aggB, WB + catOff[ci], c_ll_b[ci], zout, N);
        US* t = zin; zin = zout; zout = t;
    }
    US* zf = zin;

    // ---- graph max-pool ----
    hipMemsetAsync(enc, 0, 4096 * 4, stream);
    segmax_k<<<dim3((N + 511) / 512), dim3(256), 0, stream>>>(zf, batch, enc, N, 128);
    decode_ge<<<dim3(16), dim3(256), 0, stream>>>(enc, geb);

    // ---- node_embeddings output ----
    copy_bf2f<<<dim3(2048), dim3(256), 0, stream>>>(zf, out, (long)N * 64);

    // ---- fused heads (64 queries/block, both sides, 16 waves/block) ----
    head_fused<<<dim3((Q + 63) / 64), dim3(1024), 0, stream>>>(
        srcq, dstq, batch, zf, geb, WB,
        h1_in_b, h1_proj_b, h1_hid_b, h1_out_b, h2_in_b, h2_hid_b, h2_out_W, h2_out_b,
        out + (size_t)N * 64, out + (size_t)N * 64 + 2 * (size_t)Q, Q);
}